// Round 9
// baseline (489.443 us; speedup 1.0000x reference)
//
#include <hip/hip_runtime.h>
#include <hip/hip_bf16.h>

// Problem constants
#define NN 40960      // nodes
#define NE 163840     // edges
#define NB 1024       // graphs

typedef __attribute__((ext_vector_type(8))) short short8;
typedef __attribute__((ext_vector_type(4))) short short4v;
typedef __attribute__((ext_vector_type(4))) float floatx4;

__device__ inline unsigned short f2bf(float f) {
    union { float f; unsigned u; } v; v.f = f;
    unsigned r = v.u + 0x7fffu + ((v.u >> 16) & 1u);
    return (unsigned short)(r >> 16);
}
__device__ inline float bf2f(unsigned short s) {
    union { unsigned u; float f; } v; v.u = ((unsigned)s) << 16; return v.f;
}
__device__ inline unsigned pack2bf(float lo, float hi) {
    return (unsigned)f2bf(lo) | ((unsigned)f2bf(hi) << 16);
}

// ---------------- workspace layout (float elements) ----------------
static const size_t o_dinv = 0, o_g312 = 40960, o_g1024 = 360448, o_xc = 1409024,
                    o_f1 = 1802240, o_f2 = 2850816, o_b1v = 3375104, o_b2v = 3375232,
                    o_iws = 3375360, o_bufA = 3621124, o_bufB = 16400644;
// bufA: T @0 | U16 @+851968 | Vt16 @+2200000 (128x15360 bf16) | Wt @+3200000
//       | Wc2r @+4000000 | Wc1r @+4200000 | Btb @+4400000 (ends 5.06M)
//       | Pt1 @+6000000 (48*1024*128 fp32, ends 12.3M < 12.78M)  <- moved out of bufB
//         so the t1 GEMM can run fused/concurrent with the GCN pipeline (aggb/h16 live in bufB)
// bufB: aggb @0 (NN*80 uints max) | h16 @5.5M

// ---------------- CSR build ----------------
__global__ void k_hist(const int* __restrict__ dst, int* __restrict__ cnt) {
    int e = blockIdx.x * 256 + threadIdx.x;
    if (e < NE) atomicAdd(&cnt[dst[e]], 1);
}

__global__ __launch_bounds__(1024) void k_scan1(const int* __restrict__ cnt, int* __restrict__ offTmp,
                                                int* __restrict__ blockSum, float* __restrict__ dinv) {
    __shared__ int lds[1024];
    int tid = threadIdx.x;
    int i = blockIdx.x * 1024 + tid;
    int v = cnt[i];
    dinv[i] = rsqrtf((float)v + 1.0f);  // deg = in-count + self loop
    lds[tid] = v;
    __syncthreads();
    for (int s = 1; s < 1024; s <<= 1) {
        int t = (tid >= s) ? lds[tid - s] : 0;
        __syncthreads();
        lds[tid] += t;
        __syncthreads();
    }
    offTmp[i] = lds[tid] - v;  // local exclusive
    if (tid == 1023) blockSum[blockIdx.x] = lds[1023];
}

__global__ __launch_bounds__(64) void k_scan2(const int* __restrict__ blockSum, int* __restrict__ blockOff) {
    int l = threadIdx.x;
    int s = (l < 40) ? blockSum[l] : 0;
    int orig = s;
    for (int d = 1; d < 64; d <<= 1) {
        int t = __shfl_up(s, d);
        if (l >= d) s += t;
    }
    if (l < 40) blockOff[l] = s - orig;
}

__global__ __launch_bounds__(1024) void k_scan3(int* __restrict__ off, int* __restrict__ cur,
                                                const int* __restrict__ blockOff) {
    int i = blockIdx.x * 1024 + threadIdx.x;
    int o = off[i] + blockOff[blockIdx.x];
    off[i] = o;
    cur[i] = o;
    if (i == NN - 1) off[NN] = NE;
}

__global__ void k_fill(const int* __restrict__ ei, int* __restrict__ cur, int* __restrict__ srcOut) {
    int e = blockIdx.x * 256 + threadIdx.x;
    if (e >= NE) return;
    int s = ei[e], d = ei[NE + e];
    int pos = atomicAdd(&cur[d], 1);
    srcOut[pos] = s;
}

// ---------------- MEGA prep kernel: all weight-only preprocessing in ONE launch ----------------
// blocks [0,3328): weight transpose-convert -> Wt (7 matrices)
// blocks [3328,4828): conv-weight reshape -> Wc2r/Wc1r
// blocks [4828,7388): Btb build
// block 7388: b1v = bxt1 + sum_o bc1[o]*colsum(Wxt1,o)   (atomic-free)
// block 7389: b2v = bxt2 + sum_o bc2[o]*colsum(Wxt2,o)
// blocks [7390,7806): T build (2 o's per block)
__global__ __launch_bounds__(256) void k_prep_mega(
    const float* __restrict__ W1, const float* __restrict__ W2, const float* __restrict__ W3,
    const float* __restrict__ Wg1, const float* __restrict__ Wg2, const float* __restrict__ Wf1,
    const float* __restrict__ Wf2, unsigned short* __restrict__ Wt,
    const float* __restrict__ Wc2, const float* __restrict__ Wc1,
    float* __restrict__ Wc2r, float* __restrict__ Wc1r,
    const float* __restrict__ Wxt1, float* __restrict__ Btb,
    const float* __restrict__ bc1, const float* __restrict__ bxt1, float* __restrict__ b1v,
    const float* __restrict__ bc2, const float* __restrict__ Wxt2, const float* __restrict__ bxt2,
    float* __restrict__ b2v,
    const float* __restrict__ emb, float* __restrict__ T) {
    __shared__ float el[128];
    __shared__ float bsum[2][128];
    int bx = blockIdx.x, tid = threadIdx.x;
    if (bx < 3328) {
        const int cum[8]  = {0, 128, 320, 640, 1664, 1792, 2816, 3328};
        const int KP[7]   = {96, 96, 160, 320, 1024, 384, 1024};
        const int KB[7]   = {78, 78, 156, 312, 1024, 384, 1024};
        const int NNm[7]  = {78, 156, 312, 1024, 128, 1024, 512};
        const size_t OFF[7] = {0, 12288, 30720, 81920, 409600, 540672, 933888};
        int m = 0;
        while (m < 6 && bx >= cum[m + 1]) m++;
        int r = bx - cum[m];
        const float* src = (m == 0) ? W1 : (m == 1) ? W2 : (m == 2) ? W3 : (m == 3) ? Wg1
                         : (m == 4) ? Wg2 : (m == 5) ? Wf1 : Wf2;
        int kp = KP[m], kb = KB[m], nn = NNm[m];
        unsigned short* d = Wt + OFF[m] + (size_t)r * kp;
        for (int k = tid; k < kp; k += 256) {
            float v = (r < nn && k < kb) ? src[(size_t)k * nn + r] : 0.f;
            d[k] = f2bf(v);
        }
    } else if (bx < 4828) {
        int cc = bx - 3328, j = tid;
        const float* W = (cc < 750) ? Wc2 : Wc1;
        float* Wr = (cc < 750) ? Wc2r : Wc1r;
        int c = (cc < 750) ? cc : cc - 750;
        Wr[(size_t)c * 256 + j] = W[(size_t)(j >> 3) * 6000 + c * 8 + (j & 7)];
    } else if (bx < 7388) {
        int idx = (bx - 4828) * 256 + tid;        // < 655360 = 20*256*128
        int j = idx & 127, ok = (idx >> 7) & 255, t = idx >> 15;
        int o = ok >> 3, k = ok & 7, lpos = t - k;
        float v = (lpos >= 0 && lpos < 13) ? Wxt1[(size_t)(o * 13 + lpos) * 128 + j] : 0.f;
        Btb[(size_t)(t * 256 + ok) * 128 + j] = v;
    } else if (bx == 7388) {
        int o2 = tid >> 7, j = tid & 127;
        float p = 0.f;
        for (int o = o2; o < 32; o += 2) {
            float t = 0.f;
            for (int l = 0; l < 13; l++) t += Wxt1[(size_t)(o * 13 + l) * 128 + j];
            p += bc1[o] * t;
        }
        bsum[o2][j] = p;
        __syncthreads();
        if (tid < 128) b1v[j] = bxt1[j] + bsum[0][j] + bsum[1][j];
    } else if (bx == 7389) {
        int o2 = tid >> 7, j = tid & 127;
        float p = 0.f;
        for (int o = o2; o < 32; o += 2) {
            float t = 0.f;
            for (int l = 0; l < 121; l++) t += Wxt2[(size_t)(o * 121 + l) * 128 + j];
            p += bc2[o] * t;
        }
        bsum[o2][j] = p;
        __syncthreads();
        if (tid < 128) b2v[j] = bxt2[j] + bsum[0][j] + bsum[1][j];
    } else {
        int tb = bx - 7390;                       // < 416 = 26*16
        int v = tb >> 4, op = tb & 15;
        int o = op * 2 + (tid >> 7), j = tid & 127;
        if (tid < 128) el[j] = emb[(size_t)v * 128 + j];
        __syncthreads();
        float acc[8] = {};
        for (int l = 0; l < 121; l++) {
            float w = Wxt2[(size_t)(o * 121 + l) * 128 + j];
#pragma unroll
            for (int k = 0; k < 8; k++) acc[k] += el[l + k] * w;
        }
#pragma unroll
        for (int k = 0; k < 8; k++) T[(size_t)(v * 256 + o * 8 + k) * 128 + j] = acc[k];
    }
}

// ---------------- GCN aggregation bf16 in/out helper ----------------
__device__ inline void d_agg16_node(int n, int f, const unsigned* __restrict__ h,
                                    const float* __restrict__ dinv, const int* __restrict__ off,
                                    const int* __restrict__ srcs, unsigned* __restrict__ out, int F2) {
    if (f >= F2) return;
    float di = dinv[n];
    unsigned s0v = h[(size_t)n * F2 + f];
    float a0 = bf2f((unsigned short)(s0v & 0xffff)) * di * di;
    float a1 = bf2f((unsigned short)(s0v >> 16)) * di * di;
    int e0 = off[n], e1 = off[n + 1];
    int e = e0;
    for (; e + 4 <= e1; e += 4) {
        int s0 = srcs[e], s1 = srcs[e + 1], s2 = srcs[e + 2], s3 = srcs[e + 3];
        float d0 = dinv[s0] * di, d1 = dinv[s1] * di, d2 = dinv[s2] * di, d3 = dinv[s3] * di;
        unsigned v0 = h[(size_t)s0 * F2 + f];
        unsigned v1 = h[(size_t)s1 * F2 + f];
        unsigned v2 = h[(size_t)s2 * F2 + f];
        unsigned v3 = h[(size_t)s3 * F2 + f];
        a0 += bf2f((unsigned short)(v0 & 0xffff)) * d0 + bf2f((unsigned short)(v1 & 0xffff)) * d1
            + bf2f((unsigned short)(v2 & 0xffff)) * d2 + bf2f((unsigned short)(v3 & 0xffff)) * d3;
        a1 += bf2f((unsigned short)(v0 >> 16)) * d0 + bf2f((unsigned short)(v1 >> 16)) * d1
            + bf2f((unsigned short)(v2 >> 16)) * d2 + bf2f((unsigned short)(v3 >> 16)) * d3;
    }
    for (; e < e1; e++) {
        int s = srcs[e];
        float dd = dinv[s] * di;
        unsigned v = h[(size_t)s * F2 + f];
        a0 += bf2f((unsigned short)(v & 0xffff)) * dd;
        a1 += bf2f((unsigned short)(v >> 16)) * dd;
    }
    out[(size_t)n * F2 + f] = pack2bf(a0, a1);
}

// standalone agg16 (layer-2 input, F2=48)
__global__ void k_agg16(const unsigned* __restrict__ h, const float* __restrict__ dinv,
                        const int* __restrict__ off, const int* __restrict__ srcs,
                        unsigned* __restrict__ out, int F2) {
    d_agg16_node(blockIdx.x, threadIdx.x, h, dinv, off, srcs, out, F2);
}

// ---------------- bf16 MFMA GEMM with transposed-bf16 B: C = A @ Bt^T ----------------
#define LDST 72
template <bool ABF16, bool OUTBF16, bool ATOMIC, bool RELU_OUT>
__global__ __launch_bounds__(256) void gemm_bt(const void* __restrict__ Av, const unsigned short* __restrict__ Bt,
                                               const float* __restrict__ bias, void* __restrict__ Cv,
                                               int Nn, int Npad, int Kpad, int Klim,
                                               int lda, int ldb, int ldc, int ksplit) {
    __shared__ __align__(16) unsigned short As[64 * LDST];
    __shared__ __align__(16) unsigned short Bs[64 * LDST];
    const float* Af = (const float*)Av;
    const unsigned short* A16 = (const unsigned short*)Av;
    float* Cf = (float*)Cv;
    unsigned short* C16 = (unsigned short*)Cv;
    int bn0 = blockIdx.x * 64;
    int bm0 = blockIdx.y * 64;
    int k0 = blockIdx.z * ksplit;
    int kend = k0 + ksplit; if (kend > Kpad) kend = Kpad;
    int tid = threadIdx.x;
    int w = tid >> 6, l = tid & 63, q = l >> 4, r = l & 15;
    int wr = w >> 1, wc = w & 1;

    floatx4 acc[2][2];
#pragma unroll
    for (int i = 0; i < 2; i++)
#pragma unroll
        for (int c = 0; c < 2; c++) acc[i][c] = (floatx4)0.0f;

    int mA = tid >> 2, kcA = (tid & 3) * 8;
    int nB = tid >> 2, kcB = (tid & 3) * 8;
    int gmA = bm0 + mA;
    int gnB = bn0 + nB;

    for (int kt = k0; kt < kend; kt += 32) {
        if (ABF16) {
            *(short8*)&As[mA * LDST + kcA] = *(const short8*)(A16 + (size_t)gmA * lda + kt + kcA);
        } else {
            const float* Ap = Af + (size_t)gmA * lda + kt + kcA;
            float av[8];
            if (kt + kcA + 8 <= Klim) {
#pragma unroll
                for (int j = 0; j < 4; j++) {
                    float2 p = *(const float2*)(Ap + j * 2);
                    av[j * 2] = p.x; av[j * 2 + 1] = p.y;
                }
            } else {
#pragma unroll
                for (int j = 0; j < 8; j++) av[j] = (kt + kcA + j < Klim) ? Ap[j] : 0.f;
            }
            short8 sv;
#pragma unroll
            for (int j = 0; j < 8; j++) sv[j] = (short)f2bf(av[j]);
            *(short8*)&As[mA * LDST + kcA] = sv;
        }
        *(short8*)&Bs[nB * LDST + kcB] = *(const short8*)(Bt + (size_t)gnB * ldb + kt + kcB);
        __syncthreads();
        short8 a0 = *(const short8*)&As[(wr * 32 + r) * LDST + q * 8];
        short8 a1 = *(const short8*)&As[(wr * 32 + 16 + r) * LDST + q * 8];
        short8 b0 = *(const short8*)&Bs[(wc * 32 + r) * LDST + q * 8];
        short8 b1 = *(const short8*)&Bs[(wc * 32 + 16 + r) * LDST + q * 8];
        acc[0][0] = __builtin_amdgcn_mfma_f32_16x16x32_bf16(a0, b0, acc[0][0], 0, 0, 0);
        acc[0][1] = __builtin_amdgcn_mfma_f32_16x16x32_bf16(a0, b1, acc[0][1], 0, 0, 0);
        acc[1][0] = __builtin_amdgcn_mfma_f32_16x16x32_bf16(a1, b0, acc[1][0], 0, 0, 0);
        acc[1][1] = __builtin_amdgcn_mfma_f32_16x16x32_bf16(a1, b1, acc[1][1], 0, 0, 0);
        __syncthreads();
    }

#pragma unroll
    for (int c2 = 0; c2 < 2; c2++) {
        int col = bn0 + wc * 32 + c2 * 16 + r;
        if (col >= Npad) continue;
        bool live = col < Nn;
        float bv = (bias && live) ? bias[col] : 0.f;
#pragma unroll
        for (int i = 0; i < 2; i++) {
#pragma unroll
            for (int v = 0; v < 4; v++) {
                int row = bm0 + wr * 32 + i * 16 + q * 4 + v;
                float val = live ? (acc[i][c2][v] + bv) : 0.f;
                if (RELU_OUT) val = fmaxf(val, 0.f);
                if (OUTBF16) {
                    C16[(size_t)row * ldc + col] = live ? f2bf(val) : (unsigned short)0;
                } else if (live) {
                    if (ATOMIC) atomicAdd(&Cf[(size_t)row * ldc + col], val);
                    else Cf[(size_t)row * ldc + col] = val;
                }
            }
        }
    }
}

// ---------------- combined batched MFMA GEMM: z<26 -> U16 (flat), z>=26 -> Vt16 (packed) ----------------
__global__ __launch_bounds__(256) void k_batch_both(const float* __restrict__ Wc2r, const float* __restrict__ T,
                                                    const float* __restrict__ Wc1r, const float* __restrict__ Btb,
                                                    unsigned short* __restrict__ U16, unsigned short* __restrict__ Vt16) {
    __shared__ __align__(16) unsigned short As[64 * LDST];
    __shared__ __align__(16) unsigned short Bs[64 * LDST];
    const int M = 750, Nn = 128, K = 256;
    int z = blockIdx.z;
    bool om1 = z < 26;
    const float* A = om1 ? Wc2r : Wc1r;
    const float* Bm = om1 ? (T + (size_t)z * 32768) : (Btb + (size_t)(z - 26) * 32768);
    unsigned short* C16 = om1 ? (U16 + (size_t)z * 128) : Vt16;
    int ldc = om1 ? 3328 : 15360;
    int zz = z - 26;
    int bn0 = blockIdx.x * 64;
    int bm0 = blockIdx.y * 64;
    int tid = threadIdx.x;
    int w = tid >> 6, l = tid & 63, q = l >> 4, r = l & 15;
    int wr = w >> 1, wc = w & 1;

    floatx4 acc[2][2];
#pragma unroll
    for (int i = 0; i < 2; i++)
#pragma unroll
        for (int c = 0; c < 2; c++) acc[i][c] = (floatx4)0.0f;

    int mA = tid >> 2, kcA = (tid & 3) * 8;
    int nB = tid >> 2, kcB = (tid & 3) * 8;
    int gmA = bm0 + mA;
    int gnB = bn0 + nB;

    for (int kt = 0; kt < K; kt += 32) {
        {
            float av[8];
            const float* Ap = A + (size_t)gmA * K + kt + kcA;
            if (gmA < M) {
#pragma unroll
                for (int j = 0; j < 4; j++) {
                    float2 p = *(const float2*)(Ap + j * 2);
                    av[j * 2] = p.x; av[j * 2 + 1] = p.y;
                }
            } else {
#pragma unroll
                for (int j = 0; j < 8; j++) av[j] = 0.f;
            }
            short8 sv;
#pragma unroll
            for (int j = 0; j < 8; j++) sv[j] = (short)f2bf(av[j]);
            *(short8*)&As[mA * LDST + kcA] = sv;
        }
        {
            short8 sv;
#pragma unroll
            for (int j = 0; j < 8; j++) {
                int gk = kt + kcB + j;
                float v = (gnB < Nn) ? Bm[(size_t)gk * Nn + gnB] : 0.f;
                sv[j] = (short)f2bf(v);
            }
            *(short8*)&Bs[nB * LDST + kcB] = sv;
        }
        __syncthreads();
        short8 a0 = *(const short8*)&As[(wr * 32 + r) * LDST + q * 8];
        short8 a1 = *(const short8*)&As[(wr * 32 + 16 + r) * LDST + q * 8];
        short8 b0 = *(const short8*)&Bs[(wc * 32 + r) * LDST + q * 8];
        short8 b1 = *(const short8*)&Bs[(wc * 32 + 16 + r) * LDST + q * 8];
        acc[0][0] = __builtin_amdgcn_mfma_f32_16x16x32_bf16(a0, b0, acc[0][0], 0, 0, 0);
        acc[0][1] = __builtin_amdgcn_mfma_f32_16x16x32_bf16(a0, b1, acc[0][1], 0, 0, 0);
        acc[1][0] = __builtin_amdgcn_mfma_f32_16x16x32_bf16(a1, b0, acc[1][0], 0, 0, 0);
        acc[1][1] = __builtin_amdgcn_mfma_f32_16x16x32_bf16(a1, b1, acc[1][1], 0, 0, 0);
        __syncthreads();
    }

#pragma unroll
    for (int c = 0; c < 2; c++) {
        int col = bn0 + wc * 32 + c * 16 + r;
        if (col >= Nn) continue;
#pragma unroll
        for (int i = 0; i < 2; i++) {
#pragma unroll
            for (int v = 0; v < 4; v++) {
                int row = bm0 + wr * 32 + i * 16 + q * 4 + v;
                if (row >= M) continue;
                if (om1) C16[(size_t)row * ldc + col] = f2bf(acc[i][c][v]);
                else C16[(size_t)col * ldc + row * 20 + zz] = f2bf(acc[i][c][v]);
            }
        }
    }
}

// ---------------- fused: t1 GEMM (blocks 0..767, launched FIRST) + agg_x (4 nodes/block) ----------------
// t1: P[ks][1024][128] = A[1024,15000]fp32 @ Vt16^T, v4 full-line staged LDS pipeline (R8-verified)
#define T1LD 40
#define T1S  48
#define T1K  320
__global__ __launch_bounds__(256) void k_aggx_t1(
    const float* __restrict__ x, const float* __restrict__ dinv, const int* __restrict__ off,
    const int* __restrict__ srcs, unsigned* __restrict__ aggb,
    const float* __restrict__ t1A, const unsigned short* __restrict__ Bt, float* __restrict__ P) {
    __shared__ __align__(16) unsigned short As[2][64 * T1LD];
    __shared__ __align__(16) unsigned short Bs[2][128 * T1LD];
    int bx = blockIdx.x, tid = threadIdx.x;
    if (bx < 768) {
        // ---- t1 tile: mt = bx&15, ks = bx>>4 (same-ks blocks adjacent for B-slice L2 reuse) ----
        const int Klim = 15000;
        int mt = bx & 15, ks = bx >> 4;
        int bm0 = mt * 64;
        int k0 = ks * T1K;
        int w = tid >> 6, l = tid & 63, q = l >> 4, r = l & 15;
        int wr = w >> 1, wc = w & 1;

        floatx4 acc[2][4];
#pragma unroll
        for (int i = 0; i < 2; i++)
#pragma unroll
            for (int c = 0; c < 4; c++) acc[i][c] = (floatx4)0.0f;

        int ra = tid >> 3, ca = (tid & 7) * 4;
        int rb = tid >> 2, cb = (tid & 3) * 8;
        const float* Ap0 = t1A + (size_t)(bm0 + ra) * Klim + ca;
        const float* Ap1 = t1A + (size_t)(bm0 + ra + 32) * Klim + ca;
        const unsigned short* Bp0 = Bt + (size_t)rb * 15360 + cb;
        const unsigned short* Bp1 = Bt + (size_t)(rb + 64) * 15360 + cb;

        float4 aA0, aA1, aB0, aB1;
        short8 bA0, bA1, bB0, bB1;

        auto loadT = [&](int kt, float4& x0, float4& x1, short8& y0, short8& y1) {
            int c = kt + ca;
            if (c < Klim) {
                x0 = *(const float4*)(Ap0 + kt);
                x1 = *(const float4*)(Ap1 + kt);
            } else {
                x0 = make_float4(0.f, 0.f, 0.f, 0.f);
                x1 = make_float4(0.f, 0.f, 0.f, 0.f);
            }
            y0 = *(const short8*)(Bp0 + kt);
            y1 = *(const short8*)(Bp1 + kt);
        };
        auto stageW = [&](int buf, const float4& x0, const float4& x1, const short8& y0, const short8& y1) {
            short4v s0, s1;
            s0[0] = (short)f2bf(x0.x); s0[1] = (short)f2bf(x0.y); s0[2] = (short)f2bf(x0.z); s0[3] = (short)f2bf(x0.w);
            s1[0] = (short)f2bf(x1.x); s1[1] = (short)f2bf(x1.y); s1[2] = (short)f2bf(x1.z); s1[3] = (short)f2bf(x1.w);
            *(short4v*)&As[buf][ra * T1LD + ca] = s0;
            *(short4v*)&As[buf][(ra + 32) * T1LD + ca] = s1;
            *(short8*)&Bs[buf][rb * T1LD + cb] = y0;
            *(short8*)&Bs[buf][(rb + 64) * T1LD + cb] = y1;
        };
        auto compute = [&](int buf) {
            short8 a0 = *(const short8*)&As[buf][(wr * 32 + r) * T1LD + q * 8];
            short8 a1 = *(const short8*)&As[buf][(wr * 32 + 16 + r) * T1LD + q * 8];
            short8 b0 = *(const short8*)&Bs[buf][(wc * 64 + r) * T1LD + q * 8];
            short8 b1 = *(const short8*)&Bs[buf][(wc * 64 + 16 + r) * T1LD + q * 8];
            short8 b2 = *(const short8*)&Bs[buf][(wc * 64 + 32 + r) * T1LD + q * 8];
            short8 b3 = *(const short8*)&Bs[buf][(wc * 64 + 48 + r) * T1LD + q * 8];
            acc[0][0] = __builtin_amdgcn_mfma_f32_16x16x32_bf16(a0, b0, acc[0][0], 0, 0, 0);
            acc[0][1] = __builtin_amdgcn_mfma_f32_16x16x32_bf16(a0, b1, acc[0][1], 0, 0, 0);
            acc[0][2] = __builtin_amdgcn_mfma_f32_16x16x32_bf16(a0, b2, acc[0][2], 0, 0, 0);
            acc[0][3] = __builtin_amdgcn_mfma_f32_16x16x32_bf16(a0, b3, acc[0][3], 0, 0, 0);
            acc[1][0] = __builtin_amdgcn_mfma_f32_16x16x32_bf16(a1, b0, acc[1][0], 0, 0, 0);
            acc[1][1] = __builtin_amdgcn_mfma_f32_16x16x32_bf16(a1, b1, acc[1][1], 0, 0, 0);
            acc[1][2] = __builtin_amdgcn_mfma_f32_16x16x32_bf16(a1, b2, acc[1][2], 0, 0, 0);
            acc[1][3] = __builtin_amdgcn_mfma_f32_16x16x32_bf16(a1, b3, acc[1][3], 0, 0, 0);
        };

        loadT(k0, aA0, aA1, bA0, bA1);
        loadT(k0 + 32, aB0, aB1, bB0, bB1);
#pragma unroll
        for (int it = 0; it < T1K / 32; it += 2) {
            stageW(0, aA0, aA1, bA0, bA1);
            if (it + 2 < T1K / 32) loadT(k0 + (it + 2) * 32, aA0, aA1, bA0, bA1);
            asm volatile("s_waitcnt lgkmcnt(0)" ::: "memory");
            __builtin_amdgcn_s_barrier();
            asm volatile("" ::: "memory");
            compute(0);
            stageW(1, aB0, aB1, bB0, bB1);
            if (it + 3 < T1K / 32) loadT(k0 + (it + 3) * 32, aB0, aB1, bB0, bB1);
            asm volatile("s_waitcnt lgkmcnt(0)" ::: "memory");
            __builtin_amdgcn_s_barrier();
            asm volatile("" ::: "memory");
            compute(1);
        }

        float* Pp = P + (size_t)ks * (1024 * 128) + (size_t)bm0 * 128;
#pragma unroll
        for (int c = 0; c < 4; c++) {
            int col = wc * 64 + c * 16 + r;
#pragma unroll
            for (int i = 0; i < 2; i++) {
#pragma unroll
                for (int v = 0; v < 4; v++) {
                    int row = wr * 32 + i * 16 + q * 4 + v;
                    Pp[(size_t)row * 128 + col] = acc[i][c][v];
                }
            }
        }
    } else {
        // ---- agg_x: 4 nodes per block (one node per wave) ----
        int n = (bx - 768) * 4 + (tid >> 6);
        int f = tid & 63;
        if (f >= 48) return;
        if (f >= 39) { aggb[(size_t)n * 48 + f] = 0; return; }
        float di = dinv[n];
        float2 sv = *(const float2*)&x[(size_t)n * 78 + 2 * f];
        float a0 = sv.x * di * di, a1 = sv.y * di * di;
        int e0 = off[n], e1 = off[n + 1];
        int e = e0;
        for (; e + 4 <= e1; e += 4) {
            int s0 = srcs[e], s1 = srcs[e + 1], s2 = srcs[e + 2], s3 = srcs[e + 3];
            float d0 = dinv[s0] * di, d1 = dinv[s1] * di, d2 = dinv[s2] * di, d3 = dinv[s3] * di;
            float2 v0 = *(const float2*)&x[(size_t)s0 * 78 + 2 * f];
            float2 v1 = *(const float2*)&x[(size_t)s1 * 78 + 2 * f];
            float2 v2 = *(const float2*)&x[(size_t)s2 * 78 + 2 * f];
            float2 v3 = *(const float2*)&x[(size_t)s3 * 78 + 2 * f];
            a0 += v0.x * d0 + v1.x * d1 + v2.x * d2 + v3.x * d3;
            a1 += v0.y * d0 + v1.y * d1 + v2.y * d2 + v3.y * d3;
        }
        for (; e < e1; e++) {
            int s = srcs[e];
            float dd = dinv[s] * di;
            float2 v = *(const float2*)&x[(size_t)s * 78 + 2 * f];
            a0 += v.x * dd; a1 += v.y * dd;
        }
        aggb[(size_t)n * 48 + f] = pack2bf(a0, a1);
    }
}

// ---------------- fused: u_gather (blocks 0..1023, FIRST) + agg16 F2=80 ----------------
__global__ __launch_bounds__(128) void k_agg16_ug(
    const unsigned* __restrict__ h, const float* __restrict__ dinv, const int* __restrict__ off,
    const int* __restrict__ srcs, unsigned* __restrict__ outb,
    const int* __restrict__ t2, const unsigned short* __restrict__ U,
    const float* __restrict__ b2v, float* __restrict__ xc) {
    __shared__ int offs[752];
    __shared__ float red[8][128];
    int bx = blockIdx.x, tid = threadIdx.x;
    if (bx < NB) {
        int b = bx;
        int rg = tid >> 4, lane = tid & 15;
        const int* t2b = t2 + (size_t)b * 750;
        for (int i = tid; i < 750; i += 128) offs[i] = i * 3328 + t2b[i] * 128;
        __syncthreads();
        float a[8] = {};
#pragma unroll 4
        for (int i = rg; i < 750; i += 8) {
            short8 v = *(const short8*)&U[(size_t)offs[i] + lane * 8];
#pragma unroll
            for (int c = 0; c < 8; c++) a[c] += bf2f((unsigned short)v[c]);
        }
#pragma unroll
        for (int c = 0; c < 8; c++) red[rg][lane * 8 + c] = a[c];
        __syncthreads();
        float s = b2v[tid];
#pragma unroll
        for (int g = 0; g < 8; g++) s += red[g][tid];
        xc[(size_t)b * 384 + 256 + tid] = s;
    } else {
        d_agg16_node(bx - NB, tid, h, dinv, off, srcs, outb, 80);
    }
}

// ---------------- fused: red_t1 (blocks 0..1023, FIRST) + segmax ----------------
__global__ void k_segmax_red(const unsigned short* __restrict__ h, unsigned short* __restrict__ g,
                             const float* __restrict__ P, float* __restrict__ xc) {
    int bx = blockIdx.x, tid = threadIdx.x;
    if (bx < NB) {
        if (tid < 128) {
            int row = bx, j = tid;
            const float* p = P + (size_t)row * 128 + j;
            float s = 0.f;
#pragma unroll
            for (int ks = 0; ks < T1S; ks++) s += p[(size_t)ks * (1024 * 128)];
            xc[(size_t)row * 384 + 128 + j] += s;
        }
    } else {
        int gr = bx - NB, f = tid;
        if (f >= 320) return;
        if (f >= 312) { g[(size_t)gr * 320 + f] = 0; return; }
        float m = 0.0f;
        const unsigned short* base = h + (size_t)gr * 40 * 312 + f;
        for (int i = 0; i < 40; i++) m = fmaxf(m, bf2f(base[(size_t)i * 312]));
        g[(size_t)gr * 320 + f] = f2bf(m);
    }
}

// one-shot bias init: xc[:,0:128]=bg2, xc[:,128:256]=b1v, f2=bf2
__global__ __launch_bounds__(768) void k_initC(float* __restrict__ xc, float* __restrict__ f2,
                                               const float* __restrict__ bg2, const float* __restrict__ b1v,
                                               const float* __restrict__ bf2) {
    int b = blockIdx.x, t = threadIdx.x;
    if (t < 128) xc[(size_t)b * 384 + t] = bg2[t];
    else if (t < 256) xc[(size_t)b * 384 + t] = b1v[t - 128];
    else f2[(size_t)b * 512 + t - 256] = bf2[t - 256];
}

// out[b] = sum_j relu(f2[b,j]) * Wo[j] + bo
__global__ __launch_bounds__(64) void k_final(const float* __restrict__ f2, const float* __restrict__ Wo,
                                              const float* __restrict__ bo, float* __restrict__ out) {
    int b = blockIdx.x, lane = threadIdx.x;
    float s = 0.f;
    for (int j = lane; j < 512; j += 64) s += fmaxf(f2[(size_t)b * 512 + j], 0.f) * Wo[j];
    for (int off = 32; off; off >>= 1) s += __shfl_down(s, off);
    if (lane == 0) out[b] = s + bo[0];
}

extern "C" void kernel_launch(void* const* d_in, const int* in_sizes, int n_in,
                              void* d_out, int out_size, void* d_ws, size_t ws_size,
                              hipStream_t stream) {
    const float* x    = (const float*)d_in[0];
    const int*   ei   = (const int*)d_in[1];
    const float* t1   = (const float*)d_in[3];
    const int*   t2   = (const int*)d_in[4];
    const float* W1   = (const float*)d_in[5];
    const float* b1   = (const float*)d_in[6];
    const float* W2   = (const float*)d_in[7];
    const float* b2   = (const float*)d_in[8];
    const float* W3   = (const float*)d_in[9];
    const float* b3   = (const float*)d_in[10];
    const float* Wg1  = (const float*)d_in[11];
    const float* bg1  = (const float*)d_in[12];
    const float* Wg2  = (const float*)d_in[13];
    const float* bg2  = (const float*)d_in[14];
    const float* emb  = (const float*)d_in[15];
    const float* Wc2  = (const float*)d_in[16];
    const float* bc2  = (const float*)d_in[17];
    const float* Wxt2 = (const float*)d_in[18];
    const float* bxt2 = (const float*)d_in[19];
    const float* Wc1  = (const float*)d_in[20];
    const float* bc1  = (const float*)d_in[21];
    const float* Wxt1 = (const float*)d_in[22];
    const float* bxt1 = (const float*)d_in[23];
    const float* Wf1  = (const float*)d_in[24];
    const float* bf1  = (const float*)d_in[25];
    const float* Wf2  = (const float*)d_in[26];
    const float* bf2  = (const float*)d_in[27];
    const float* Wo   = (const float*)d_in[28];
    const float* bo   = (const float*)d_in[29];
    float* out = (float*)d_out;

    float* ws = (float*)d_ws;
    float* dinv  = ws + o_dinv;
    unsigned short* g312b = (unsigned short*)(ws + o_g312);   // 1024 x 320 bf16
    unsigned short* g1024b = (unsigned short*)(ws + o_g1024); // 1024 x 1024 bf16
    float* xc    = ws + o_xc;     // [1024 x 384] fp32
    unsigned short* f1b = (unsigned short*)(ws + o_f1);       // 1024 x 1024 bf16
    float* f2    = ws + o_f2;
    float* b1v   = ws + o_b1v;
    float* b2v   = ws + o_b2v;
    int* csrOff  = (int*)(ws + o_iws);
    int* csrCur  = csrOff + (NN + 1);
    int* csrSrc  = csrCur + NN;
    int* blockSum = (int*)(ws + o_f1 + 600000);  // scratch, dead before f1b written
    int* blockOff = blockSum + 40;
    float* bufA  = ws + o_bufA;
    float* bufB  = ws + o_bufB;
    float* T    = bufA;
    unsigned short* U16  = (unsigned short*)(bufA + 851968);
    unsigned short* Vt16 = (unsigned short*)(bufA + 2200000);  // 128 x 15360 bf16
    unsigned short* Wt   = (unsigned short*)(bufA + 3200000);  // transposed weights
    float* Wc2r = bufA + 4000000;
    float* Wc1r = bufA + 4200000;
    float* Btb  = bufA + 4400000;
    float* Pt1  = bufA + 6000000;  // t1 split-K partials (48*1024*128 fp32) -- clear of Btb (ends 5.06M)
    // bf16 node pipeline (inside bufB)
    unsigned* aggb = (unsigned*)bufB;                          // NN*80 uints max
    unsigned short* h16 = (unsigned short*)(bufB + 5500000);   // up to NN*312

    unsigned short* W1t  = Wt + 0;
    unsigned short* W2t  = Wt + 12288;
    unsigned short* W3t  = Wt + 30720;
    unsigned short* Wg1t = Wt + 81920;
    unsigned short* Wg2t = Wt + 409600;
    unsigned short* Wf1t = Wt + 540672;
    unsigned short* Wf2t = Wt + 933888;

    // ---- memsets (no deps) + CSR build ----
    hipMemsetAsync(Vt16, 0, (size_t)128 * 15360 * 2, stream);
    hipMemsetAsync(csrCur, 0, NN * sizeof(int), stream);
    k_hist<<<NE / 256, 256, 0, stream>>>(ei + NE, csrCur);
    k_scan1<<<40, 1024, 0, stream>>>(csrCur, csrOff, blockSum, dinv);
    k_scan2<<<1, 64, 0, stream>>>(blockSum, blockOff);
    k_scan3<<<40, 1024, 0, stream>>>(csrOff, csrCur, blockOff);
    k_fill<<<NE / 256, 256, 0, stream>>>(ei, csrCur, csrSrc);

    // ---- all weight-only preprocessing in one launch ----
    k_prep_mega<<<7806, 256, 0, stream>>>(W1, W2, W3, Wg1, Wg2, Wf1, Wf2, Wt,
                                          Wc2, Wc1, Wc2r, Wc1r,
                                          Wxt1, Btb, bc1, bxt1, b1v,
                                          bc2, Wxt2, bxt2, b2v, emb, T);

    // ---- both batched GEMMs (U16 + Vt16) in one launch ----
    k_batch_both<<<dim3(2, 12, 46), 256, 0, stream>>>(Wc2r, T, Wc1r, Btb, U16, Vt16);

    // ---- bias C-inits (xc, f2) ----
    k_initC<<<NB, 768, 0, stream>>>(xc, f2, bg2, b1v, bf2);

    // ---- fused: t1 GEMM (first 768 blocks) + agg_x (10240 blocks x 4 nodes) ----
    k_aggx_t1<<<768 + NN / 4, 256, 0, stream>>>(x, dinv, csrOff, csrSrc, aggb, t1, Vt16, Pt1);

    // ---- GCN pipeline ----
    gemm_bt<true, true, false, true><<<dim3(2, 640, 1), 256, 0, stream>>>(
        aggb, W1t, b1, h16, 78, 96, 96, 96, 96, 96, 96, 96);
    k_agg16<<<NN, 64, 0, stream>>>((unsigned*)h16, dinv, csrOff, csrSrc, aggb, 48);
    gemm_bt<true, true, false, true><<<dim3(3, 640, 1), 256, 0, stream>>>(
        aggb, W2t, b2, h16, 156, 160, 96, 96, 96, 96, 160, 96);
    // fused: u_gather (first 1024 blocks) + agg16 F2=80
    k_agg16_ug<<<NB + NN, 128, 0, stream>>>((unsigned*)h16, dinv, csrOff, csrSrc, aggb,
                                            t2, U16, b2v, xc);
    gemm_bt<true, true, false, true><<<dim3(5, 640, 1), 256, 0, stream>>>(
        aggb, W3t, b3, h16, 312, 312, 160, 160, 160, 160, 312, 160);
    // fused: red_t1 (first 1024 blocks) + segmax
    k_segmax_red<<<2 * NB, 320, 0, stream>>>(h16, g312b, Pt1, xc);
    gemm_bt<true, true, false, true><<<dim3(16, 16, 1), 256, 0, stream>>>(
        g312b, Wg1t, bg1, g1024b, 1024, 1024, 320, 320, 320, 320, 1024, 320);

    // xc[:,0:128] = g1024 @ Wg2 + bg2   (split-K atomic)
    gemm_bt<true, false, true, false><<<dim3(2, 16, 8), 256, 0, stream>>>(
        g1024b, Wg2t, nullptr, xc + 0, 128, 128, 1024, 1024, 1024, 1024, 384, 128);

    // ---- head ----
    gemm_bt<false, true, false, true><<<dim3(16, 16, 1), 256, 0, stream>>>(
        xc, Wf1t, bf1, f1b, 1024, 1024, 384, 384, 384, 384, 1024, 384);
    gemm_bt<true, false, true, false><<<dim3(8, 16, 4), 256, 0, stream>>>(
        f1b, Wf2t, nullptr, f2, 512, 512, 1024, 1024, 1024, 1024, 512, 256);
    k_final<<<NB, 64, 0, stream>>>(f2, Wo, bo, out);
}

// Round 10
// 447.035 us; speedup vs baseline: 1.0949x; 1.0949x over previous
//
#include <hip/hip_runtime.h>
#include <hip/hip_bf16.h>

// Problem constants
#define NN 40960      // nodes
#define NE 163840     // edges
#define NB 1024       // graphs

typedef __attribute__((ext_vector_type(8))) short short8;
typedef __attribute__((ext_vector_type(4))) short short4v;
typedef __attribute__((ext_vector_type(4))) float floatx4;

__device__ inline unsigned short f2bf(float f) {
    union { float f; unsigned u; } v; v.f = f;
    unsigned r = v.u + 0x7fffu + ((v.u >> 16) & 1u);
    return (unsigned short)(r >> 16);
}
__device__ inline float bf2f(unsigned short s) {
    union { unsigned u; float f; } v; v.u = ((unsigned)s) << 16; return v.f;
}
__device__ inline unsigned pack2bf(float lo, float hi) {
    return (unsigned)f2bf(lo) | ((unsigned)f2bf(hi) << 16);
}

// ---------------- workspace layout (float elements) ----------------
static const size_t o_dinv = 0, o_g312 = 40960, o_g1024 = 360448, o_xc = 1409024,
                    o_f1 = 1802240, o_f2 = 2850816, o_b1v = 3375104, o_b2v = 3375232,
                    o_iws = 3375360, o_bufA = 3621124, o_bufB = 16400644;
// bufA: T @0 | U16 @+851968 | Vt16 @+2200000 (128x15360 bf16) | Wt @+3200000
//       | Wc2r @+4000000 | Wc1r @+4200000 | Btb @+4400000 (ends 5.06M)
//       | Pt1 @+6000000 (48*1024*128 fp32, ends 12.3M < 12.78M)
// bufB: aggb @0 (NN*80 uints max) | h16 @5.5M

// ---------------- CSR build ----------------
__global__ void k_hist(const int* __restrict__ dst, int* __restrict__ cnt) {
    int e = blockIdx.x * 256 + threadIdx.x;
    if (e < NE) atomicAdd(&cnt[dst[e]], 1);
}

__global__ __launch_bounds__(1024) void k_scan1(const int* __restrict__ cnt, int* __restrict__ offTmp,
                                                int* __restrict__ blockSum, float* __restrict__ dinv) {
    __shared__ int lds[1024];
    int tid = threadIdx.x;
    int i = blockIdx.x * 1024 + tid;
    int v = cnt[i];
    dinv[i] = rsqrtf((float)v + 1.0f);  // deg = in-count + self loop
    lds[tid] = v;
    __syncthreads();
    for (int s = 1; s < 1024; s <<= 1) {
        int t = (tid >= s) ? lds[tid - s] : 0;
        __syncthreads();
        lds[tid] += t;
        __syncthreads();
    }
    offTmp[i] = lds[tid] - v;  // local exclusive
    if (tid == 1023) blockSum[blockIdx.x] = lds[1023];
}

__global__ __launch_bounds__(64) void k_scan2(const int* __restrict__ blockSum, int* __restrict__ blockOff) {
    int l = threadIdx.x;
    int s = (l < 40) ? blockSum[l] : 0;
    int orig = s;
    for (int d = 1; d < 64; d <<= 1) {
        int t = __shfl_up(s, d);
        if (l >= d) s += t;
    }
    if (l < 40) blockOff[l] = s - orig;
}

__global__ __launch_bounds__(1024) void k_scan3(int* __restrict__ off, int* __restrict__ cur,
                                                const int* __restrict__ blockOff) {
    int i = blockIdx.x * 1024 + threadIdx.x;
    int o = off[i] + blockOff[blockIdx.x];
    off[i] = o;
    cur[i] = o;
    if (i == NN - 1) off[NN] = NE;
}

__global__ void k_fill(const int* __restrict__ ei, int* __restrict__ cur, int* __restrict__ srcOut) {
    int e = blockIdx.x * 256 + threadIdx.x;
    if (e >= NE) return;
    int s = ei[e], d = ei[NE + e];
    int pos = atomicAdd(&cur[d], 1);
    srcOut[pos] = s;
}

// ---------------- MEGA prep kernel: all weight-only preprocessing in ONE launch ----------------
// blocks [0,3328): weight transpose-convert -> Wt (7 matrices)
// blocks [3328,4828): conv-weight reshape -> Wc2r/Wc1r
// blocks [4828,7388): Btb build
// blocks [7388,7452): bias folds, 64 PARALLEL blocks (one o each) with atomicAdd
//   (R9's 2-block serial version was a 77us latency tail — b1v/b2v pre-zeroed by memset)
// blocks [7452,7868): T build (2 o's per block)
__global__ __launch_bounds__(256) void k_prep_mega(
    const float* __restrict__ W1, const float* __restrict__ W2, const float* __restrict__ W3,
    const float* __restrict__ Wg1, const float* __restrict__ Wg2, const float* __restrict__ Wf1,
    const float* __restrict__ Wf2, unsigned short* __restrict__ Wt,
    const float* __restrict__ Wc2, const float* __restrict__ Wc1,
    float* __restrict__ Wc2r, float* __restrict__ Wc1r,
    const float* __restrict__ Wxt1, float* __restrict__ Btb,
    const float* __restrict__ bc1, const float* __restrict__ bxt1, float* __restrict__ b1v,
    const float* __restrict__ bc2, const float* __restrict__ Wxt2, const float* __restrict__ bxt2,
    float* __restrict__ b2v,
    const float* __restrict__ emb, float* __restrict__ T) {
    __shared__ float el[128];
    int bx = blockIdx.x, tid = threadIdx.x;
    if (bx < 3328) {
        const int cum[8]  = {0, 128, 320, 640, 1664, 1792, 2816, 3328};
        const int KP[7]   = {96, 96, 160, 320, 1024, 384, 1024};
        const int KB[7]   = {78, 78, 156, 312, 1024, 384, 1024};
        const int NNm[7]  = {78, 156, 312, 1024, 128, 1024, 512};
        const size_t OFF[7] = {0, 12288, 30720, 81920, 409600, 540672, 933888};
        int m = 0;
        while (m < 6 && bx >= cum[m + 1]) m++;
        int r = bx - cum[m];
        const float* src = (m == 0) ? W1 : (m == 1) ? W2 : (m == 2) ? W3 : (m == 3) ? Wg1
                         : (m == 4) ? Wg2 : (m == 5) ? Wf1 : Wf2;
        int kp = KP[m], kb = KB[m], nn = NNm[m];
        unsigned short* d = Wt + OFF[m] + (size_t)r * kp;
        for (int k = tid; k < kp; k += 256) {
            float v = (r < nn && k < kb) ? src[(size_t)k * nn + r] : 0.f;
            d[k] = f2bf(v);
        }
    } else if (bx < 4828) {
        int cc = bx - 3328, j = tid;
        const float* W = (cc < 750) ? Wc2 : Wc1;
        float* Wr = (cc < 750) ? Wc2r : Wc1r;
        int c = (cc < 750) ? cc : cc - 750;
        Wr[(size_t)c * 256 + j] = W[(size_t)(j >> 3) * 6000 + c * 8 + (j & 7)];
    } else if (bx < 7388) {
        int idx = (bx - 4828) * 256 + tid;        // < 655360 = 20*256*128
        int j = idx & 127, ok = (idx >> 7) & 255, t = idx >> 15;
        int o = ok >> 3, k = ok & 7, lpos = t - k;
        float v = (lpos >= 0 && lpos < 13) ? Wxt1[(size_t)(o * 13 + lpos) * 128 + j] : 0.f;
        Btb[(size_t)(t * 256 + ok) * 128 + j] = v;
    } else if (bx < 7452) {
        // bias folds: 64 parallel blocks, one o each (b1v/b2v pre-zeroed via memset)
        if (tid >= 128) return;
        int b = bx - 7388, j = tid;
        if (b < 32) {
            const float* p = Wxt1 + (size_t)b * 13 * 128 + j;
            float t = 0.f;
            for (int l = 0; l < 13; l++) t += p[(size_t)l * 128];
            float add = bc1[b] * t + ((b == 0) ? bxt1[j] : 0.f);
            atomicAdd(&b1v[j], add);
        } else {
            int o = b - 32;
            const float* p = Wxt2 + (size_t)o * 121 * 128 + j;
            float t = 0.f;
            for (int l = 0; l < 121; l++) t += p[(size_t)l * 128];
            float add = bc2[o] * t + ((o == 0) ? bxt2[j] : 0.f);
            atomicAdd(&b2v[j], add);
        }
    } else {
        int tb = bx - 7452;                       // < 416 = 26*16
        int v = tb >> 4, op = tb & 15;
        int o = op * 2 + (tid >> 7), j = tid & 127;
        if (tid < 128) el[j] = emb[(size_t)v * 128 + j];
        __syncthreads();
        float acc[8] = {};
        for (int l = 0; l < 121; l++) {
            float w = Wxt2[(size_t)(o * 121 + l) * 128 + j];
#pragma unroll
            for (int k = 0; k < 8; k++) acc[k] += el[l + k] * w;
        }
#pragma unroll
        for (int k = 0; k < 8; k++) T[(size_t)(v * 256 + o * 8 + k) * 128 + j] = acc[k];
    }
}

// ---------------- GCN aggregation bf16 in/out helper ----------------
__device__ inline void d_agg16_node(int n, int f, const unsigned* __restrict__ h,
                                    const float* __restrict__ dinv, const int* __restrict__ off,
                                    const int* __restrict__ srcs, unsigned* __restrict__ out, int F2) {
    if (f >= F2) return;
    float di = dinv[n];
    unsigned s0v = h[(size_t)n * F2 + f];
    float a0 = bf2f((unsigned short)(s0v & 0xffff)) * di * di;
    float a1 = bf2f((unsigned short)(s0v >> 16)) * di * di;
    int e0 = off[n], e1 = off[n + 1];
    int e = e0;
    for (; e + 4 <= e1; e += 4) {
        int s0 = srcs[e], s1 = srcs[e + 1], s2 = srcs[e + 2], s3 = srcs[e + 3];
        float d0 = dinv[s0] * di, d1 = dinv[s1] * di, d2 = dinv[s2] * di, d3 = dinv[s3] * di;
        unsigned v0 = h[(size_t)s0 * F2 + f];
        unsigned v1 = h[(size_t)s1 * F2 + f];
        unsigned v2 = h[(size_t)s2 * F2 + f];
        unsigned v3 = h[(size_t)s3 * F2 + f];
        a0 += bf2f((unsigned short)(v0 & 0xffff)) * d0 + bf2f((unsigned short)(v1 & 0xffff)) * d1
            + bf2f((unsigned short)(v2 & 0xffff)) * d2 + bf2f((unsigned short)(v3 & 0xffff)) * d3;
        a1 += bf2f((unsigned short)(v0 >> 16)) * d0 + bf2f((unsigned short)(v1 >> 16)) * d1
            + bf2f((unsigned short)(v2 >> 16)) * d2 + bf2f((unsigned short)(v3 >> 16)) * d3;
    }
    for (; e < e1; e++) {
        int s = srcs[e];
        float dd = dinv[s] * di;
        unsigned v = h[(size_t)s * F2 + f];
        a0 += bf2f((unsigned short)(v & 0xffff)) * dd;
        a1 += bf2f((unsigned short)(v >> 16)) * dd;
    }
    out[(size_t)n * F2 + f] = pack2bf(a0, a1);
}

// standalone agg16 (layer-2 input, F2=48)
__global__ void k_agg16(const unsigned* __restrict__ h, const float* __restrict__ dinv,
                        const int* __restrict__ off, const int* __restrict__ srcs,
                        unsigned* __restrict__ out, int F2) {
    d_agg16_node(blockIdx.x, threadIdx.x, h, dinv, off, srcs, out, F2);
}

// ---------------- bf16 MFMA GEMM with transposed-bf16 B: C = A @ Bt^T ----------------
#define LDST 72
template <bool ABF16, bool OUTBF16, bool ATOMIC, bool RELU_OUT>
__global__ __launch_bounds__(256) void gemm_bt(const void* __restrict__ Av, const unsigned short* __restrict__ Bt,
                                               const float* __restrict__ bias, void* __restrict__ Cv,
                                               int Nn, int Npad, int Kpad, int Klim,
                                               int lda, int ldb, int ldc, int ksplit) {
    __shared__ __align__(16) unsigned short As[64 * LDST];
    __shared__ __align__(16) unsigned short Bs[64 * LDST];
    const float* Af = (const float*)Av;
    const unsigned short* A16 = (const unsigned short*)Av;
    float* Cf = (float*)Cv;
    unsigned short* C16 = (unsigned short*)Cv;
    int bn0 = blockIdx.x * 64;
    int bm0 = blockIdx.y * 64;
    int k0 = blockIdx.z * ksplit;
    int kend = k0 + ksplit; if (kend > Kpad) kend = Kpad;
    int tid = threadIdx.x;
    int w = tid >> 6, l = tid & 63, q = l >> 4, r = l & 15;
    int wr = w >> 1, wc = w & 1;

    floatx4 acc[2][2];
#pragma unroll
    for (int i = 0; i < 2; i++)
#pragma unroll
        for (int c = 0; c < 2; c++) acc[i][c] = (floatx4)0.0f;

    int mA = tid >> 2, kcA = (tid & 3) * 8;
    int nB = tid >> 2, kcB = (tid & 3) * 8;
    int gmA = bm0 + mA;
    int gnB = bn0 + nB;

    for (int kt = k0; kt < kend; kt += 32) {
        if (ABF16) {
            *(short8*)&As[mA * LDST + kcA] = *(const short8*)(A16 + (size_t)gmA * lda + kt + kcA);
        } else {
            const float* Ap = Af + (size_t)gmA * lda + kt + kcA;
            float av[8];
            if (kt + kcA + 8 <= Klim) {
#pragma unroll
                for (int j = 0; j < 4; j++) {
                    float2 p = *(const float2*)(Ap + j * 2);
                    av[j * 2] = p.x; av[j * 2 + 1] = p.y;
                }
            } else {
#pragma unroll
                for (int j = 0; j < 8; j++) av[j] = (kt + kcA + j < Klim) ? Ap[j] : 0.f;
            }
            short8 sv;
#pragma unroll
            for (int j = 0; j < 8; j++) sv[j] = (short)f2bf(av[j]);
            *(short8*)&As[mA * LDST + kcA] = sv;
        }
        *(short8*)&Bs[nB * LDST + kcB] = *(const short8*)(Bt + (size_t)gnB * ldb + kt + kcB);
        __syncthreads();
        short8 a0 = *(const short8*)&As[(wr * 32 + r) * LDST + q * 8];
        short8 a1 = *(const short8*)&As[(wr * 32 + 16 + r) * LDST + q * 8];
        short8 b0 = *(const short8*)&Bs[(wc * 32 + r) * LDST + q * 8];
        short8 b1 = *(const short8*)&Bs[(wc * 32 + 16 + r) * LDST + q * 8];
        acc[0][0] = __builtin_amdgcn_mfma_f32_16x16x32_bf16(a0, b0, acc[0][0], 0, 0, 0);
        acc[0][1] = __builtin_amdgcn_mfma_f32_16x16x32_bf16(a0, b1, acc[0][1], 0, 0, 0);
        acc[1][0] = __builtin_amdgcn_mfma_f32_16x16x32_bf16(a1, b0, acc[1][0], 0, 0, 0);
        acc[1][1] = __builtin_amdgcn_mfma_f32_16x16x32_bf16(a1, b1, acc[1][1], 0, 0, 0);
        __syncthreads();
    }

#pragma unroll
    for (int c2 = 0; c2 < 2; c2++) {
        int col = bn0 + wc * 32 + c2 * 16 + r;
        if (col >= Npad) continue;
        bool live = col < Nn;
        float bv = (bias && live) ? bias[col] : 0.f;
#pragma unroll
        for (int i = 0; i < 2; i++) {
#pragma unroll
            for (int v = 0; v < 4; v++) {
                int row = bm0 + wr * 32 + i * 16 + q * 4 + v;
                float val = live ? (acc[i][c2][v] + bv) : 0.f;
                if (RELU_OUT) val = fmaxf(val, 0.f);
                if (OUTBF16) {
                    C16[(size_t)row * ldc + col] = live ? f2bf(val) : (unsigned short)0;
                } else if (live) {
                    if (ATOMIC) atomicAdd(&Cf[(size_t)row * ldc + col], val);
                    else Cf[(size_t)row * ldc + col] = val;
                }
            }
        }
    }
}

// ---------------- combined batched MFMA GEMM: z<26 -> U16 (flat), z>=26 -> Vt16 (packed) ----------------
__global__ __launch_bounds__(256) void k_batch_both(const float* __restrict__ Wc2r, const float* __restrict__ T,
                                                    const float* __restrict__ Wc1r, const float* __restrict__ Btb,
                                                    unsigned short* __restrict__ U16, unsigned short* __restrict__ Vt16) {
    __shared__ __align__(16) unsigned short As[64 * LDST];
    __shared__ __align__(16) unsigned short Bs[64 * LDST];
    const int M = 750, Nn = 128, K = 256;
    int z = blockIdx.z;
    bool om1 = z < 26;
    const float* A = om1 ? Wc2r : Wc1r;
    const float* Bm = om1 ? (T + (size_t)z * 32768) : (Btb + (size_t)(z - 26) * 32768);
    unsigned short* C16 = om1 ? (U16 + (size_t)z * 128) : Vt16;
    int ldc = om1 ? 3328 : 15360;
    int zz = z - 26;
    int bn0 = blockIdx.x * 64;
    int bm0 = blockIdx.y * 64;
    int tid = threadIdx.x;
    int w = tid >> 6, l = tid & 63, q = l >> 4, r = l & 15;
    int wr = w >> 1, wc = w & 1;

    floatx4 acc[2][2];
#pragma unroll
    for (int i = 0; i < 2; i++)
#pragma unroll
        for (int c = 0; c < 2; c++) acc[i][c] = (floatx4)0.0f;

    int mA = tid >> 2, kcA = (tid & 3) * 8;
    int nB = tid >> 2, kcB = (tid & 3) * 8;
    int gmA = bm0 + mA;
    int gnB = bn0 + nB;

    for (int kt = 0; kt < K; kt += 32) {
        {
            float av[8];
            const float* Ap = A + (size_t)gmA * K + kt + kcA;
            if (gmA < M) {
#pragma unroll
                for (int j = 0; j < 4; j++) {
                    float2 p = *(const float2*)(Ap + j * 2);
                    av[j * 2] = p.x; av[j * 2 + 1] = p.y;
                }
            } else {
#pragma unroll
                for (int j = 0; j < 8; j++) av[j] = 0.f;
            }
            short8 sv;
#pragma unroll
            for (int j = 0; j < 8; j++) sv[j] = (short)f2bf(av[j]);
            *(short8*)&As[mA * LDST + kcA] = sv;
        }
        {
            short8 sv;
#pragma unroll
            for (int j = 0; j < 8; j++) {
                int gk = kt + kcB + j;
                float v = (gnB < Nn) ? Bm[(size_t)gk * Nn + gnB] : 0.f;
                sv[j] = (short)f2bf(v);
            }
            *(short8*)&Bs[nB * LDST + kcB] = sv;
        }
        __syncthreads();
        short8 a0 = *(const short8*)&As[(wr * 32 + r) * LDST + q * 8];
        short8 a1 = *(const short8*)&As[(wr * 32 + 16 + r) * LDST + q * 8];
        short8 b0 = *(const short8*)&Bs[(wc * 32 + r) * LDST + q * 8];
        short8 b1 = *(const short8*)&Bs[(wc * 32 + 16 + r) * LDST + q * 8];
        acc[0][0] = __builtin_amdgcn_mfma_f32_16x16x32_bf16(a0, b0, acc[0][0], 0, 0, 0);
        acc[0][1] = __builtin_amdgcn_mfma_f32_16x16x32_bf16(a0, b1, acc[0][1], 0, 0, 0);
        acc[1][0] = __builtin_amdgcn_mfma_f32_16x16x32_bf16(a1, b0, acc[1][0], 0, 0, 0);
        acc[1][1] = __builtin_amdgcn_mfma_f32_16x16x32_bf16(a1, b1, acc[1][1], 0, 0, 0);
        __syncthreads();
    }

#pragma unroll
    for (int c = 0; c < 2; c++) {
        int col = bn0 + wc * 32 + c * 16 + r;
        if (col >= Nn) continue;
#pragma unroll
        for (int i = 0; i < 2; i++) {
#pragma unroll
            for (int v = 0; v < 4; v++) {
                int row = bm0 + wr * 32 + i * 16 + q * 4 + v;
                if (row >= M) continue;
                if (om1) C16[(size_t)row * ldc + col] = f2bf(acc[i][c][v]);
                else C16[(size_t)col * ldc + row * 20 + zz] = f2bf(acc[i][c][v]);
            }
        }
    }
}

// ---------------- fused: t1 GEMM (blocks 0..767, launched FIRST) + agg_x (4 nodes/block) ----------------
// t1: P[ks][1024][128] = A[1024,15000]fp32 @ Vt16^T, v4 full-line staged LDS pipeline (R8-verified)
#define T1LD 40
#define T1S  48
#define T1K  320
__global__ __launch_bounds__(256) void k_aggx_t1(
    const float* __restrict__ x, const float* __restrict__ dinv, const int* __restrict__ off,
    const int* __restrict__ srcs, unsigned* __restrict__ aggb,
    const float* __restrict__ t1A, const unsigned short* __restrict__ Bt, float* __restrict__ P) {
    __shared__ __align__(16) unsigned short As[2][64 * T1LD];
    __shared__ __align__(16) unsigned short Bs[2][128 * T1LD];
    int bx = blockIdx.x, tid = threadIdx.x;
    if (bx < 768) {
        // ---- t1 tile: mt = bx&15, ks = bx>>4 (same-ks blocks adjacent for B-slice L2 reuse) ----
        const int Klim = 15000;
        int mt = bx & 15, ks = bx >> 4;
        int bm0 = mt * 64;
        int k0 = ks * T1K;
        int w = tid >> 6, l = tid & 63, q = l >> 4, r = l & 15;
        int wr = w >> 1, wc = w & 1;

        floatx4 acc[2][4];
#pragma unroll
        for (int i = 0; i < 2; i++)
#pragma unroll
            for (int c = 0; c < 4; c++) acc[i][c] = (floatx4)0.0f;

        int ra = tid >> 3, ca = (tid & 7) * 4;
        int rb = tid >> 2, cb = (tid & 3) * 8;
        const float* Ap0 = t1A + (size_t)(bm0 + ra) * Klim + ca;
        const float* Ap1 = t1A + (size_t)(bm0 + ra + 32) * Klim + ca;
        const unsigned short* Bp0 = Bt + (size_t)rb * 15360 + cb;
        const unsigned short* Bp1 = Bt + (size_t)(rb + 64) * 15360 + cb;

        float4 aA0, aA1, aB0, aB1;
        short8 bA0, bA1, bB0, bB1;

        auto loadT = [&](int kt, float4& x0, float4& x1, short8& y0, short8& y1) {
            int c = kt + ca;
            if (c < Klim) {
                x0 = *(const float4*)(Ap0 + kt);
                x1 = *(const float4*)(Ap1 + kt);
            } else {
                x0 = make_float4(0.f, 0.f, 0.f, 0.f);
                x1 = make_float4(0.f, 0.f, 0.f, 0.f);
            }
            y0 = *(const short8*)(Bp0 + kt);
            y1 = *(const short8*)(Bp1 + kt);
        };
        auto stageW = [&](int buf, const float4& x0, const float4& x1, const short8& y0, const short8& y1) {
            short4v s0, s1;
            s0[0] = (short)f2bf(x0.x); s0[1] = (short)f2bf(x0.y); s0[2] = (short)f2bf(x0.z); s0[3] = (short)f2bf(x0.w);
            s1[0] = (short)f2bf(x1.x); s1[1] = (short)f2bf(x1.y); s1[2] = (short)f2bf(x1.z); s1[3] = (short)f2bf(x1.w);
            *(short4v*)&As[buf][ra * T1LD + ca] = s0;
            *(short4v*)&As[buf][(ra + 32) * T1LD + ca] = s1;
            *(short8*)&Bs[buf][rb * T1LD + cb] = y0;
            *(short8*)&Bs[buf][(rb + 64) * T1LD + cb] = y1;
        };
        auto compute = [&](int buf) {
            short8 a0 = *(const short8*)&As[buf][(wr * 32 + r) * T1LD + q * 8];
            short8 a1 = *(const short8*)&As[buf][(wr * 32 + 16 + r) * T1LD + q * 8];
            short8 b0 = *(const short8*)&Bs[buf][(wc * 64 + r) * T1LD + q * 8];
            short8 b1 = *(const short8*)&Bs[buf][(wc * 64 + 16 + r) * T1LD + q * 8];
            short8 b2 = *(const short8*)&Bs[buf][(wc * 64 + 32 + r) * T1LD + q * 8];
            short8 b3 = *(const short8*)&Bs[buf][(wc * 64 + 48 + r) * T1LD + q * 8];
            acc[0][0] = __builtin_amdgcn_mfma_f32_16x16x32_bf16(a0, b0, acc[0][0], 0, 0, 0);
            acc[0][1] = __builtin_amdgcn_mfma_f32_16x16x32_bf16(a0, b1, acc[0][1], 0, 0, 0);
            acc[0][2] = __builtin_amdgcn_mfma_f32_16x16x32_bf16(a0, b2, acc[0][2], 0, 0, 0);
            acc[0][3] = __builtin_amdgcn_mfma_f32_16x16x32_bf16(a0, b3, acc[0][3], 0, 0, 0);
            acc[1][0] = __builtin_amdgcn_mfma_f32_16x16x32_bf16(a1, b0, acc[1][0], 0, 0, 0);
            acc[1][1] = __builtin_amdgcn_mfma_f32_16x16x32_bf16(a1, b1, acc[1][1], 0, 0, 0);
            acc[1][2] = __builtin_amdgcn_mfma_f32_16x16x32_bf16(a1, b2, acc[1][2], 0, 0, 0);
            acc[1][3] = __builtin_amdgcn_mfma_f32_16x16x32_bf16(a1, b3, acc[1][3], 0, 0, 0);
        };

        loadT(k0, aA0, aA1, bA0, bA1);
        loadT(k0 + 32, aB0, aB1, bB0, bB1);
#pragma unroll
        for (int it = 0; it < T1K / 32; it += 2) {
            stageW(0, aA0, aA1, bA0, bA1);
            if (it + 2 < T1K / 32) loadT(k0 + (it + 2) * 32, aA0, aA1, bA0, bA1);
            asm volatile("s_waitcnt lgkmcnt(0)" ::: "memory");
            __builtin_amdgcn_s_barrier();
            asm volatile("" ::: "memory");
            compute(0);
            stageW(1, aB0, aB1, bB0, bB1);
            if (it + 3 < T1K / 32) loadT(k0 + (it + 3) * 32, aB0, aB1, bB0, bB1);
            asm volatile("s_waitcnt lgkmcnt(0)" ::: "memory");
            __builtin_amdgcn_s_barrier();
            asm volatile("" ::: "memory");
            compute(1);
        }

        float* Pp = P + (size_t)ks * (1024 * 128) + (size_t)bm0 * 128;
#pragma unroll
        for (int c = 0; c < 4; c++) {
            int col = wc * 64 + c * 16 + r;
#pragma unroll
            for (int i = 0; i < 2; i++) {
#pragma unroll
                for (int v = 0; v < 4; v++) {
                    int row = wr * 32 + i * 16 + q * 4 + v;
                    Pp[(size_t)row * 128 + col] = acc[i][c][v];
                }
            }
        }
    } else {
        // ---- agg_x: 4 nodes per block (one node per wave) ----
        int n = (bx - 768) * 4 + (tid >> 6);
        int f = tid & 63;
        if (f >= 48) return;
        if (f >= 39) { aggb[(size_t)n * 48 + f] = 0; return; }
        float di = dinv[n];
        float2 sv = *(const float2*)&x[(size_t)n * 78 + 2 * f];
        float a0 = sv.x * di * di, a1 = sv.y * di * di;
        int e0 = off[n], e1 = off[n + 1];
        int e = e0;
        for (; e + 4 <= e1; e += 4) {
            int s0 = srcs[e], s1 = srcs[e + 1], s2 = srcs[e + 2], s3 = srcs[e + 3];
            float d0 = dinv[s0] * di, d1 = dinv[s1] * di, d2 = dinv[s2] * di, d3 = dinv[s3] * di;
            float2 v0 = *(const float2*)&x[(size_t)s0 * 78 + 2 * f];
            float2 v1 = *(const float2*)&x[(size_t)s1 * 78 + 2 * f];
            float2 v2 = *(const float2*)&x[(size_t)s2 * 78 + 2 * f];
            float2 v3 = *(const float2*)&x[(size_t)s3 * 78 + 2 * f];
            a0 += v0.x * d0 + v1.x * d1 + v2.x * d2 + v3.x * d3;
            a1 += v0.y * d0 + v1.y * d1 + v2.y * d2 + v3.y * d3;
        }
        for (; e < e1; e++) {
            int s = srcs[e];
            float dd = dinv[s] * di;
            float2 v = *(const float2*)&x[(size_t)s * 78 + 2 * f];
            a0 += v.x * dd; a1 += v.y * dd;
        }
        aggb[(size_t)n * 48 + f] = pack2bf(a0, a1);
    }
}

// ---------------- fused: u_gather (blocks 0..1023, FIRST) + agg16 F2=80 ----------------
__global__ __launch_bounds__(128) void k_agg16_ug(
    const unsigned* __restrict__ h, const float* __restrict__ dinv, const int* __restrict__ off,
    const int* __restrict__ srcs, unsigned* __restrict__ outb,
    const int* __restrict__ t2, const unsigned short* __restrict__ U,
    const float* __restrict__ b2v, float* __restrict__ xc) {
    __shared__ int offs[752];
    __shared__ float red[8][128];
    int bx = blockIdx.x, tid = threadIdx.x;
    if (bx < NB) {
        int b = bx;
        int rg = tid >> 4, lane = tid & 15;
        const int* t2b = t2 + (size_t)b * 750;
        for (int i = tid; i < 750; i += 128) offs[i] = i * 3328 + t2b[i] * 128;
        __syncthreads();
        float a[8] = {};
#pragma unroll 4
        for (int i = rg; i < 750; i += 8) {
            short8 v = *(const short8*)&U[(size_t)offs[i] + lane * 8];
#pragma unroll
            for (int c = 0; c < 8; c++) a[c] += bf2f((unsigned short)v[c]);
        }
#pragma unroll
        for (int c = 0; c < 8; c++) red[rg][lane * 8 + c] = a[c];
        __syncthreads();
        float s = b2v[tid];
#pragma unroll
        for (int g = 0; g < 8; g++) s += red[g][tid];
        xc[(size_t)b * 384 + 256 + tid] = s;
    } else {
        d_agg16_node(bx - NB, tid, h, dinv, off, srcs, outb, 80);
    }
}

// ---------------- fused: red_t1 (blocks 0..1023, FIRST) + segmax ----------------
__global__ void k_segmax_red(const unsigned short* __restrict__ h, unsigned short* __restrict__ g,
                             const float* __restrict__ P, float* __restrict__ xc) {
    int bx = blockIdx.x, tid = threadIdx.x;
    if (bx < NB) {
        if (tid < 128) {
            int row = bx, j = tid;
            const float* p = P + (size_t)row * 128 + j;
            float s = 0.f;
#pragma unroll
            for (int ks = 0; ks < T1S; ks++) s += p[(size_t)ks * (1024 * 128)];
            xc[(size_t)row * 384 + 128 + j] += s;
        }
    } else {
        int gr = bx - NB, f = tid;
        if (f >= 320) return;
        if (f >= 312) { g[(size_t)gr * 320 + f] = 0; return; }
        float m = 0.0f;
        const unsigned short* base = h + (size_t)gr * 40 * 312 + f;
        for (int i = 0; i < 40; i++) m = fmaxf(m, bf2f(base[(size_t)i * 312]));
        g[(size_t)gr * 320 + f] = f2bf(m);
    }
}

// one-shot bias init: xc[:,0:128]=bg2, xc[:,128:256]=b1v, f2=bf2
__global__ __launch_bounds__(768) void k_initC(float* __restrict__ xc, float* __restrict__ f2,
                                               const float* __restrict__ bg2, const float* __restrict__ b1v,
                                               const float* __restrict__ bf2) {
    int b = blockIdx.x, t = threadIdx.x;
    if (t < 128) xc[(size_t)b * 384 + t] = bg2[t];
    else if (t < 256) xc[(size_t)b * 384 + t] = b1v[t - 128];
    else f2[(size_t)b * 512 + t - 256] = bf2[t - 256];
}

// out[b] = sum_j relu(f2[b,j]) * Wo[j] + bo
__global__ __launch_bounds__(64) void k_final(const float* __restrict__ f2, const float* __restrict__ Wo,
                                              const float* __restrict__ bo, float* __restrict__ out) {
    int b = blockIdx.x, lane = threadIdx.x;
    float s = 0.f;
    for (int j = lane; j < 512; j += 64) s += fmaxf(f2[(size_t)b * 512 + j], 0.f) * Wo[j];
    for (int off = 32; off; off >>= 1) s += __shfl_down(s, off);
    if (lane == 0) out[b] = s + bo[0];
}

extern "C" void kernel_launch(void* const* d_in, const int* in_sizes, int n_in,
                              void* d_out, int out_size, void* d_ws, size_t ws_size,
                              hipStream_t stream) {
    const float* x    = (const float*)d_in[0];
    const int*   ei   = (const int*)d_in[1];
    const float* t1   = (const float*)d_in[3];
    const int*   t2   = (const int*)d_in[4];
    const float* W1   = (const float*)d_in[5];
    const float* b1   = (const float*)d_in[6];
    const float* W2   = (const float*)d_in[7];
    const float* b2   = (const float*)d_in[8];
    const float* W3   = (const float*)d_in[9];
    const float* b3   = (const float*)d_in[10];
    const float* Wg1  = (const float*)d_in[11];
    const float* bg1  = (const float*)d_in[12];
    const float* Wg2  = (const float*)d_in[13];
    const float* bg2  = (const float*)d_in[14];
    const float* emb  = (const float*)d_in[15];
    const float* Wc2  = (const float*)d_in[16];
    const float* bc2  = (const float*)d_in[17];
    const float* Wxt2 = (const float*)d_in[18];
    const float* bxt2 = (const float*)d_in[19];
    const float* Wc1  = (const float*)d_in[20];
    const float* bc1  = (const float*)d_in[21];
    const float* Wxt1 = (const float*)d_in[22];
    const float* bxt1 = (const float*)d_in[23];
    const float* Wf1  = (const float*)d_in[24];
    const float* bf1  = (const float*)d_in[25];
    const float* Wf2  = (const float*)d_in[26];
    const float* bf2  = (const float*)d_in[27];
    const float* Wo   = (const float*)d_in[28];
    const float* bo   = (const float*)d_in[29];
    float* out = (float*)d_out;

    float* ws = (float*)d_ws;
    float* dinv  = ws + o_dinv;
    unsigned short* g312b = (unsigned short*)(ws + o_g312);   // 1024 x 320 bf16
    unsigned short* g1024b = (unsigned short*)(ws + o_g1024); // 1024 x 1024 bf16
    float* xc    = ws + o_xc;     // [1024 x 384] fp32
    unsigned short* f1b = (unsigned short*)(ws + o_f1);       // 1024 x 1024 bf16
    float* f2    = ws + o_f2;
    float* b1v   = ws + o_b1v;
    float* b2v   = ws + o_b2v;
    int* csrOff  = (int*)(ws + o_iws);
    int* csrCur  = csrOff + (NN + 1);
    int* csrSrc  = csrCur + NN;
    int* blockSum = (int*)(ws + o_f1 + 600000);  // scratch, dead before f1b written
    int* blockOff = blockSum + 40;
    float* bufA  = ws + o_bufA;
    float* bufB  = ws + o_bufB;
    float* T    = bufA;
    unsigned short* U16  = (unsigned short*)(bufA + 851968);
    unsigned short* Vt16 = (unsigned short*)(bufA + 2200000);  // 128 x 15360 bf16
    unsigned short* Wt   = (unsigned short*)(bufA + 3200000);  // transposed weights
    float* Wc2r = bufA + 4000000;
    float* Wc1r = bufA + 4200000;
    float* Btb  = bufA + 4400000;
    float* Pt1  = bufA + 6000000;  // t1 split-K partials (48*1024*128 fp32) -- clear of Btb (ends 5.06M)
    // bf16 node pipeline (inside bufB)
    unsigned* aggb = (unsigned*)bufB;                          // NN*80 uints max
    unsigned short* h16 = (unsigned short*)(bufB + 5500000);   // up to NN*312

    unsigned short* W1t  = Wt + 0;
    unsigned short* W2t  = Wt + 12288;
    unsigned short* W3t  = Wt + 30720;
    unsigned short* Wg1t = Wt + 81920;
    unsigned short* Wg2t = Wt + 409600;
    unsigned short* Wf1t = Wt + 540672;
    unsigned short* Wf2t = Wt + 933888;

    // ---- memsets (no deps) + CSR build ----
    hipMemsetAsync(Vt16, 0, (size_t)128 * 15360 * 2, stream);
    hipMemsetAsync(b1v, 0, 256 * sizeof(float), stream);   // b1v+b2v contiguous; atomic bias folds need zero
    hipMemsetAsync(csrCur, 0, NN * sizeof(int), stream);
    k_hist<<<NE / 256, 256, 0, stream>>>(ei + NE, csrCur);
    k_scan1<<<40, 1024, 0, stream>>>(csrCur, csrOff, blockSum, dinv);
    k_scan2<<<1, 64, 0, stream>>>(blockSum, blockOff);
    k_scan3<<<40, 1024, 0, stream>>>(csrOff, csrCur, blockOff);
    k_fill<<<NE / 256, 256, 0, stream>>>(ei, csrCur, csrSrc);

    // ---- all weight-only preprocessing in one launch ----
    k_prep_mega<<<7868, 256, 0, stream>>>(W1, W2, W3, Wg1, Wg2, Wf1, Wf2, Wt,
                                          Wc2, Wc1, Wc2r, Wc1r,
                                          Wxt1, Btb, bc1, bxt1, b1v,
                                          bc2, Wxt2, bxt2, b2v, emb, T);

    // ---- both batched GEMMs (U16 + Vt16) in one launch ----
    k_batch_both<<<dim3(2, 12, 46), 256, 0, stream>>>(Wc2r, T, Wc1r, Btb, U16, Vt16);

    // ---- bias C-inits (xc, f2) ----
    k_initC<<<NB, 768, 0, stream>>>(xc, f2, bg2, b1v, bf2);

    // ---- fused: t1 GEMM (first 768 blocks) + agg_x (10240 blocks x 4 nodes) ----
    k_aggx_t1<<<768 + NN / 4, 256, 0, stream>>>(x, dinv, csrOff, csrSrc, aggb, t1, Vt16, Pt1);

    // ---- GCN pipeline ----
    gemm_bt<true, true, false, true><<<dim3(2, 640, 1), 256, 0, stream>>>(
        aggb, W1t, b1, h16, 78, 96, 96, 96, 96, 96, 96, 96);
    k_agg16<<<NN, 64, 0, stream>>>((unsigned*)h16, dinv, csrOff, csrSrc, aggb, 48);
    gemm_bt<true, true, false, true><<<dim3(3, 640, 1), 256, 0, stream>>>(
        aggb, W2t, b2, h16, 156, 160, 96, 96, 96, 96, 160, 96);
    // fused: u_gather (first 1024 blocks) + agg16 F2=80
    k_agg16_ug<<<NB + NN, 128, 0, stream>>>((unsigned*)h16, dinv, csrOff, csrSrc, aggb,
                                            t2, U16, b2v, xc);
    gemm_bt<true, true, false, true><<<dim3(5, 640, 1), 256, 0, stream>>>(
        aggb, W3t, b3, h16, 312, 312, 160, 160, 160, 160, 312, 160);
    // fused: red_t1 (first 1024 blocks) + segmax
    k_segmax_red<<<2 * NB, 320, 0, stream>>>(h16, g312b, Pt1, xc);
    gemm_bt<true, true, false, true><<<dim3(16, 16, 1), 256, 0, stream>>>(
        g312b, Wg1t, bg1, g1024b, 1024, 1024, 320, 320, 320, 320, 1024, 320);

    // xc[:,0:128] = g1024 @ Wg2 + bg2   (split-K atomic)
    gemm_bt<true, false, true, false><<<dim3(2, 16, 8), 256, 0, stream>>>(
        g1024b, Wg2t, nullptr, xc + 0, 128, 128, 1024, 1024, 1024, 1024, 384, 128);

    // ---- head ----
    gemm_bt<false, true, false, true><<<dim3(16, 16, 1), 256, 0, stream>>>(
        xc, Wf1t, bf1, f1b, 1024, 1024, 384, 384, 384, 384, 1024, 384);
    gemm_bt<true, false, true, false><<<dim3(8, 16, 4), 256, 0, stream>>>(
        f1b, Wf2t, nullptr, f2, 512, 512, 1024, 1024, 1024, 1024, 512, 256);
    k_final<<<NB, 64, 0, stream>>>(f2, Wo, bo, out);
}

// Round 11
// 423.337 us; speedup vs baseline: 1.1562x; 1.0560x over previous
//
#include <hip/hip_runtime.h>
#include <hip/hip_bf16.h>

// Problem constants
#define NN 40960      // nodes
#define NE 163840     // edges
#define NB 1024       // graphs

typedef __attribute__((ext_vector_type(8))) short short8;
typedef __attribute__((ext_vector_type(4))) short short4v;
typedef __attribute__((ext_vector_type(4))) float floatx4;

__device__ inline unsigned short f2bf(float f) {
    union { float f; unsigned u; } v; v.f = f;
    unsigned r = v.u + 0x7fffu + ((v.u >> 16) & 1u);
    return (unsigned short)(r >> 16);
}
__device__ inline float bf2f(unsigned short s) {
    union { unsigned u; float f; } v; v.u = ((unsigned)s) << 16; return v.f;
}
__device__ inline unsigned pack2bf(float lo, float hi) {
    return (unsigned)f2bf(lo) | ((unsigned)f2bf(hi) << 16);
}

// ---------------- workspace layout (float elements) ----------------
static const size_t o_dinv = 0, o_g312 = 40960, o_g1024 = 360448, o_xc = 1409024,
                    o_f1 = 1802240, o_f2 = 2850816, o_b1v = 3375104, o_b2v = 3375232,
                    o_iws = 3375360, o_bufA = 3621124, o_bufB = 16400644;
// bufA: T @0 | U16 @+851968 | Vt16 @+2200000 (128x15360 bf16) | Wt @+3200000
//       | Wc2r @+4000000 | Wc1r @+4200000 | Btb @+4400000 (ends 5.06M)
//       | Pt1 @+6000000 (48*1024*128 fp32, ends 12.3M < 12.78M)
// bufB: aggb @0 (NN*80 uints max) | h16 @5.5M

// ---------------- CSR build ----------------
__global__ void k_hist(const int* __restrict__ dst, int* __restrict__ cnt) {
    int e = blockIdx.x * 256 + threadIdx.x;
    if (e < NE) atomicAdd(&cnt[dst[e]], 1);
}

__global__ __launch_bounds__(1024) void k_scan1(const int* __restrict__ cnt, int* __restrict__ offTmp,
                                                int* __restrict__ blockSum, float* __restrict__ dinv) {
    __shared__ int lds[1024];
    int tid = threadIdx.x;
    int i = blockIdx.x * 1024 + tid;
    int v = cnt[i];
    dinv[i] = rsqrtf((float)v + 1.0f);  // deg = in-count + self loop
    lds[tid] = v;
    __syncthreads();
    for (int s = 1; s < 1024; s <<= 1) {
        int t = (tid >= s) ? lds[tid - s] : 0;
        __syncthreads();
        lds[tid] += t;
        __syncthreads();
    }
    offTmp[i] = lds[tid] - v;  // local exclusive
    if (tid == 1023) blockSum[blockIdx.x] = lds[1023];
}

__global__ __launch_bounds__(64) void k_scan2(const int* __restrict__ blockSum, int* __restrict__ blockOff) {
    int l = threadIdx.x;
    int s = (l < 40) ? blockSum[l] : 0;
    int orig = s;
    for (int d = 1; d < 64; d <<= 1) {
        int t = __shfl_up(s, d);
        if (l >= d) s += t;
    }
    if (l < 40) blockOff[l] = s - orig;
}

__global__ __launch_bounds__(1024) void k_scan3(int* __restrict__ off, int* __restrict__ cur,
                                                const int* __restrict__ blockOff) {
    int i = blockIdx.x * 1024 + threadIdx.x;
    int o = off[i] + blockOff[blockIdx.x];
    off[i] = o;
    cur[i] = o;
    if (i == NN - 1) off[NN] = NE;
}

// ---------------- MEGA prep kernel: all weight-only preprocessing in ONE launch ----------------
// blocks [0,3328): weight transpose-convert -> Wt (7 matrices)
// blocks [3328,4828): conv-weight reshape -> Wc2r/Wc1r
// blocks [4828,7388): Btb build
// blocks [7388,7452): bias folds, 64 PARALLEL blocks (one o each) with atomicAdd
// blocks [7452,7868): T build (2 o's per block)
__global__ __launch_bounds__(256) void k_prep_mega(
    const float* __restrict__ W1, const float* __restrict__ W2, const float* __restrict__ W3,
    const float* __restrict__ Wg1, const float* __restrict__ Wg2, const float* __restrict__ Wf1,
    const float* __restrict__ Wf2, unsigned short* __restrict__ Wt,
    const float* __restrict__ Wc2, const float* __restrict__ Wc1,
    float* __restrict__ Wc2r, float* __restrict__ Wc1r,
    const float* __restrict__ Wxt1, float* __restrict__ Btb,
    const float* __restrict__ bc1, const float* __restrict__ bxt1, float* __restrict__ b1v,
    const float* __restrict__ bc2, const float* __restrict__ Wxt2, const float* __restrict__ bxt2,
    float* __restrict__ b2v,
    const float* __restrict__ emb, float* __restrict__ T) {
    __shared__ float el[128];
    int bx = blockIdx.x, tid = threadIdx.x;
    if (bx < 3328) {
        const int cum[8]  = {0, 128, 320, 640, 1664, 1792, 2816, 3328};
        const int KP[7]   = {96, 96, 160, 320, 1024, 384, 1024};
        const int KB[7]   = {78, 78, 156, 312, 1024, 384, 1024};
        const int NNm[7]  = {78, 156, 312, 1024, 128, 1024, 512};
        const size_t OFF[7] = {0, 12288, 30720, 81920, 409600, 540672, 933888};
        int m = 0;
        while (m < 6 && bx >= cum[m + 1]) m++;
        int r = bx - cum[m];
        const float* src = (m == 0) ? W1 : (m == 1) ? W2 : (m == 2) ? W3 : (m == 3) ? Wg1
                         : (m == 4) ? Wg2 : (m == 5) ? Wf1 : Wf2;
        int kp = KP[m], kb = KB[m], nn = NNm[m];
        unsigned short* d = Wt + OFF[m] + (size_t)r * kp;
        for (int k = tid; k < kp; k += 256) {
            float v = (r < nn && k < kb) ? src[(size_t)k * nn + r] : 0.f;
            d[k] = f2bf(v);
        }
    } else if (bx < 4828) {
        int cc = bx - 3328, j = tid;
        const float* W = (cc < 750) ? Wc2 : Wc1;
        float* Wr = (cc < 750) ? Wc2r : Wc1r;
        int c = (cc < 750) ? cc : cc - 750;
        Wr[(size_t)c * 256 + j] = W[(size_t)(j >> 3) * 6000 + c * 8 + (j & 7)];
    } else if (bx < 7388) {
        int idx = (bx - 4828) * 256 + tid;        // < 655360 = 20*256*128
        int j = idx & 127, ok = (idx >> 7) & 255, t = idx >> 15;
        int o = ok >> 3, k = ok & 7, lpos = t - k;
        float v = (lpos >= 0 && lpos < 13) ? Wxt1[(size_t)(o * 13 + lpos) * 128 + j] : 0.f;
        Btb[(size_t)(t * 256 + ok) * 128 + j] = v;
    } else if (bx < 7452) {
        if (tid >= 128) return;
        int b = bx - 7388, j = tid;
        if (b < 32) {
            const float* p = Wxt1 + (size_t)b * 13 * 128 + j;
            float t = 0.f;
            for (int l = 0; l < 13; l++) t += p[(size_t)l * 128];
            float add = bc1[b] * t + ((b == 0) ? bxt1[j] : 0.f);
            atomicAdd(&b1v[j], add);
        } else {
            int o = b - 32;
            const float* p = Wxt2 + (size_t)o * 121 * 128 + j;
            float t = 0.f;
            for (int l = 0; l < 121; l++) t += p[(size_t)l * 128];
            float add = bc2[o] * t + ((o == 0) ? bxt2[j] : 0.f);
            atomicAdd(&b2v[j], add);
        }
    } else {
        int tb = bx - 7452;                       // < 416 = 26*16
        int v = tb >> 4, op = tb & 15;
        int o = op * 2 + (tid >> 7), j = tid & 127;
        if (tid < 128) el[j] = emb[(size_t)v * 128 + j];
        __syncthreads();
        float acc[8] = {};
        for (int l = 0; l < 121; l++) {
            float w = Wxt2[(size_t)(o * 121 + l) * 128 + j];
#pragma unroll
            for (int k = 0; k < 8; k++) acc[k] += el[l + k] * w;
        }
#pragma unroll
        for (int k = 0; k < 8; k++) T[(size_t)(v * 256 + o * 8 + k) * 128 + j] = acc[k];
    }
}

// ---------------- GCN aggregation, layer 1: fp32 x in, bf16 out padded to 96 (standalone, full occ) ----
__global__ __launch_bounds__(64) void k_agg_x(const float* __restrict__ x, const float* __restrict__ dinv,
                                              const int* __restrict__ off, const int* __restrict__ srcs,
                                              unsigned* __restrict__ out) {
    int n = blockIdx.x;
    int f = threadIdx.x;          // uint column (2 floats)
    if (f >= 48) return;
    if (f >= 39) { out[(size_t)n * 48 + f] = 0; return; }
    float di = dinv[n];
    float2 sv = *(const float2*)&x[(size_t)n * 78 + 2 * f];
    float a0 = sv.x * di * di, a1 = sv.y * di * di;
    int e0 = off[n], e1 = off[n + 1];
    int e = e0;
    for (; e + 4 <= e1; e += 4) {
        int s0 = srcs[e], s1 = srcs[e + 1], s2 = srcs[e + 2], s3 = srcs[e + 3];
        float d0 = dinv[s0] * di, d1 = dinv[s1] * di, d2 = dinv[s2] * di, d3 = dinv[s3] * di;
        float2 v0 = *(const float2*)&x[(size_t)s0 * 78 + 2 * f];
        float2 v1 = *(const float2*)&x[(size_t)s1 * 78 + 2 * f];
        float2 v2 = *(const float2*)&x[(size_t)s2 * 78 + 2 * f];
        float2 v3 = *(const float2*)&x[(size_t)s3 * 78 + 2 * f];
        a0 += v0.x * d0 + v1.x * d1 + v2.x * d2 + v3.x * d3;
        a1 += v0.y * d0 + v1.y * d1 + v2.y * d2 + v3.y * d3;
    }
    for (; e < e1; e++) {
        int s = srcs[e];
        float dd = dinv[s] * di;
        float2 v = *(const float2*)&x[(size_t)s * 78 + 2 * f];
        a0 += v.x * dd; a1 += v.y * dd;
    }
    out[(size_t)n * 48 + f] = pack2bf(a0, a1);
}

// ---------------- GCN aggregation bf16 in/out helper ----------------
__device__ inline void d_agg16_node(int n, int f, const unsigned* __restrict__ h,
                                    const float* __restrict__ dinv, const int* __restrict__ off,
                                    const int* __restrict__ srcs, unsigned* __restrict__ out, int F2) {
    if (f >= F2) return;
    float di = dinv[n];
    unsigned s0v = h[(size_t)n * F2 + f];
    float a0 = bf2f((unsigned short)(s0v & 0xffff)) * di * di;
    float a1 = bf2f((unsigned short)(s0v >> 16)) * di * di;
    int e0 = off[n], e1 = off[n + 1];
    int e = e0;
    for (; e + 4 <= e1; e += 4) {
        int s0 = srcs[e], s1 = srcs[e + 1], s2 = srcs[e + 2], s3 = srcs[e + 3];
        float d0 = dinv[s0] * di, d1 = dinv[s1] * di, d2 = dinv[s2] * di, d3 = dinv[s3] * di;
        unsigned v0 = h[(size_t)s0 * F2 + f];
        unsigned v1 = h[(size_t)s1 * F2 + f];
        unsigned v2 = h[(size_t)s2 * F2 + f];
        unsigned v3 = h[(size_t)s3 * F2 + f];
        a0 += bf2f((unsigned short)(v0 & 0xffff)) * d0 + bf2f((unsigned short)(v1 & 0xffff)) * d1
            + bf2f((unsigned short)(v2 & 0xffff)) * d2 + bf2f((unsigned short)(v3 & 0xffff)) * d3;
        a1 += bf2f((unsigned short)(v0 >> 16)) * d0 + bf2f((unsigned short)(v1 >> 16)) * d1
            + bf2f((unsigned short)(v2 >> 16)) * d2 + bf2f((unsigned short)(v3 >> 16)) * d3;
    }
    for (; e < e1; e++) {
        int s = srcs[e];
        float dd = dinv[s] * di;
        unsigned v = h[(size_t)s * F2 + f];
        a0 += bf2f((unsigned short)(v & 0xffff)) * dd;
        a1 += bf2f((unsigned short)(v >> 16)) * dd;
    }
    out[(size_t)n * F2 + f] = pack2bf(a0, a1);
}

// standalone agg16 (layer-2 input, F2=48)
__global__ void k_agg16(const unsigned* __restrict__ h, const float* __restrict__ dinv,
                        const int* __restrict__ off, const int* __restrict__ srcs,
                        unsigned* __restrict__ out, int F2) {
    d_agg16_node(blockIdx.x, threadIdx.x, h, dinv, off, srcs, out, F2);
}

// ---------------- bf16 MFMA GEMM with transposed-bf16 B: C = A @ Bt^T ----------------
#define LDST 72
template <bool ABF16, bool OUTBF16, bool ATOMIC, bool RELU_OUT>
__global__ __launch_bounds__(256) void gemm_bt(const void* __restrict__ Av, const unsigned short* __restrict__ Bt,
                                               const float* __restrict__ bias, void* __restrict__ Cv,
                                               int Nn, int Npad, int Kpad, int Klim,
                                               int lda, int ldb, int ldc, int ksplit) {
    __shared__ __align__(16) unsigned short As[64 * LDST];
    __shared__ __align__(16) unsigned short Bs[64 * LDST];
    const float* Af = (const float*)Av;
    const unsigned short* A16 = (const unsigned short*)Av;
    float* Cf = (float*)Cv;
    unsigned short* C16 = (unsigned short*)Cv;
    int bn0 = blockIdx.x * 64;
    int bm0 = blockIdx.y * 64;
    int k0 = blockIdx.z * ksplit;
    int kend = k0 + ksplit; if (kend > Kpad) kend = Kpad;
    int tid = threadIdx.x;
    int w = tid >> 6, l = tid & 63, q = l >> 4, r = l & 15;
    int wr = w >> 1, wc = w & 1;

    floatx4 acc[2][2];
#pragma unroll
    for (int i = 0; i < 2; i++)
#pragma unroll
        for (int c = 0; c < 2; c++) acc[i][c] = (floatx4)0.0f;

    int mA = tid >> 2, kcA = (tid & 3) * 8;
    int nB = tid >> 2, kcB = (tid & 3) * 8;
    int gmA = bm0 + mA;
    int gnB = bn0 + nB;

    for (int kt = k0; kt < kend; kt += 32) {
        if (ABF16) {
            *(short8*)&As[mA * LDST + kcA] = *(const short8*)(A16 + (size_t)gmA * lda + kt + kcA);
        } else {
            const float* Ap = Af + (size_t)gmA * lda + kt + kcA;
            float av[8];
            if (kt + kcA + 8 <= Klim) {
#pragma unroll
                for (int j = 0; j < 4; j++) {
                    float2 p = *(const float2*)(Ap + j * 2);
                    av[j * 2] = p.x; av[j * 2 + 1] = p.y;
                }
            } else {
#pragma unroll
                for (int j = 0; j < 8; j++) av[j] = (kt + kcA + j < Klim) ? Ap[j] : 0.f;
            }
            short8 sv;
#pragma unroll
            for (int j = 0; j < 8; j++) sv[j] = (short)f2bf(av[j]);
            *(short8*)&As[mA * LDST + kcA] = sv;
        }
        *(short8*)&Bs[nB * LDST + kcB] = *(const short8*)(Bt + (size_t)gnB * ldb + kt + kcB);
        __syncthreads();
        short8 a0 = *(const short8*)&As[(wr * 32 + r) * LDST + q * 8];
        short8 a1 = *(const short8*)&As[(wr * 32 + 16 + r) * LDST + q * 8];
        short8 b0 = *(const short8*)&Bs[(wc * 32 + r) * LDST + q * 8];
        short8 b1 = *(const short8*)&Bs[(wc * 32 + 16 + r) * LDST + q * 8];
        acc[0][0] = __builtin_amdgcn_mfma_f32_16x16x32_bf16(a0, b0, acc[0][0], 0, 0, 0);
        acc[0][1] = __builtin_amdgcn_mfma_f32_16x16x32_bf16(a0, b1, acc[0][1], 0, 0, 0);
        acc[1][0] = __builtin_amdgcn_mfma_f32_16x16x32_bf16(a1, b0, acc[1][0], 0, 0, 0);
        acc[1][1] = __builtin_amdgcn_mfma_f32_16x16x32_bf16(a1, b1, acc[1][1], 0, 0, 0);
        __syncthreads();
    }

#pragma unroll
    for (int c2 = 0; c2 < 2; c2++) {
        int col = bn0 + wc * 32 + c2 * 16 + r;
        if (col >= Npad) continue;
        bool live = col < Nn;
        float bv = (bias && live) ? bias[col] : 0.f;
#pragma unroll
        for (int i = 0; i < 2; i++) {
#pragma unroll
            for (int v = 0; v < 4; v++) {
                int row = bm0 + wr * 32 + i * 16 + q * 4 + v;
                float val = live ? (acc[i][c2][v] + bv) : 0.f;
                if (RELU_OUT) val = fmaxf(val, 0.f);
                if (OUTBF16) {
                    C16[(size_t)row * ldc + col] = live ? f2bf(val) : (unsigned short)0;
                } else if (live) {
                    if (ATOMIC) atomicAdd(&Cf[(size_t)row * ldc + col], val);
                    else Cf[(size_t)row * ldc + col] = val;
                }
            }
        }
    }
}

// ---------------- fused: k_fill + batch_both + initC (mutually independent) ----------------
// blocks [0,640): CSR fill; [640,1744): batched GEMMs (z<26->U16, z>=26->Vt16); [1744,2768): initC
__global__ __launch_bounds__(256) void k_fbi(
    const int* __restrict__ ei, int* __restrict__ cur, int* __restrict__ srcOut,
    const float* __restrict__ Wc2r, const float* __restrict__ T,
    const float* __restrict__ Wc1r, const float* __restrict__ Btb,
    unsigned short* __restrict__ U16, unsigned short* __restrict__ Vt16,
    float* __restrict__ xc, float* __restrict__ f2,
    const float* __restrict__ bg2, const float* __restrict__ b1v, const float* __restrict__ bf2) {
    __shared__ __align__(16) unsigned short As[64 * LDST];
    __shared__ __align__(16) unsigned short Bs[64 * LDST];
    int bx = blockIdx.x, tid = threadIdx.x;
    if (bx < 640) {
        int e = bx * 256 + tid;
        if (e >= NE) return;
        int s = ei[e], d = ei[NE + e];
        int pos = atomicAdd(&cur[d], 1);
        srcOut[pos] = s;
        return;
    }
    if (bx >= 1744) {
        int b = bx - 1744;
        for (int t = tid; t < 768; t += 256) {
            if (t < 128) xc[(size_t)b * 384 + t] = bg2[t];
            else if (t < 256) xc[(size_t)b * 384 + t] = b1v[t - 128];
            else f2[(size_t)b * 512 + t - 256] = bf2[t - 256];
        }
        return;
    }
    // ---- batch_both: v = bx-640 -> (gx, gy, gz) of dim3(2,12,46) ----
    int v = bx - 640;
    int gx = v & 1, gy = (v >> 1) % 12, gz = (v >> 1) / 12;
    const int M = 750, Nn = 128, K = 256;
    bool om1 = gz < 26;
    const float* A = om1 ? Wc2r : Wc1r;
    const float* Bm = om1 ? (T + (size_t)gz * 32768) : (Btb + (size_t)(gz - 26) * 32768);
    unsigned short* C16 = om1 ? (U16 + (size_t)gz * 128) : Vt16;
    int ldc = om1 ? 3328 : 15360;
    int zz = gz - 26;
    int bn0 = gx * 64;
    int bm0 = gy * 64;
    int w = tid >> 6, l = tid & 63, q = l >> 4, r = l & 15;
    int wr = w >> 1, wc = w & 1;

    floatx4 acc[2][2];
#pragma unroll
    for (int i = 0; i < 2; i++)
#pragma unroll
        for (int c = 0; c < 2; c++) acc[i][c] = (floatx4)0.0f;

    int mA = tid >> 2, kcA = (tid & 3) * 8;
    int nB = tid >> 2, kcB = (tid & 3) * 8;
    int gmA = bm0 + mA;
    int gnB = bn0 + nB;

    for (int kt = 0; kt < K; kt += 32) {
        {
            float av[8];
            const float* Ap = A + (size_t)gmA * K + kt + kcA;
            if (gmA < M) {
#pragma unroll
                for (int j = 0; j < 4; j++) {
                    float2 p = *(const float2*)(Ap + j * 2);
                    av[j * 2] = p.x; av[j * 2 + 1] = p.y;
                }
            } else {
#pragma unroll
                for (int j = 0; j < 8; j++) av[j] = 0.f;
            }
            short8 sv;
#pragma unroll
            for (int j = 0; j < 8; j++) sv[j] = (short)f2bf(av[j]);
            *(short8*)&As[mA * LDST + kcA] = sv;
        }
        {
            short8 sv;
#pragma unroll
            for (int j = 0; j < 8; j++) {
                int gk = kt + kcB + j;
                float vv = (gnB < Nn) ? Bm[(size_t)gk * Nn + gnB] : 0.f;
                sv[j] = (short)f2bf(vv);
            }
            *(short8*)&Bs[nB * LDST + kcB] = sv;
        }
        __syncthreads();
        short8 a0 = *(const short8*)&As[(wr * 32 + r) * LDST + q * 8];
        short8 a1 = *(const short8*)&As[(wr * 32 + 16 + r) * LDST + q * 8];
        short8 b0 = *(const short8*)&Bs[(wc * 32 + r) * LDST + q * 8];
        short8 b1 = *(const short8*)&Bs[(wc * 32 + 16 + r) * LDST + q * 8];
        acc[0][0] = __builtin_amdgcn_mfma_f32_16x16x32_bf16(a0, b0, acc[0][0], 0, 0, 0);
        acc[0][1] = __builtin_amdgcn_mfma_f32_16x16x32_bf16(a0, b1, acc[0][1], 0, 0, 0);
        acc[1][0] = __builtin_amdgcn_mfma_f32_16x16x32_bf16(a1, b0, acc[1][0], 0, 0, 0);
        acc[1][1] = __builtin_amdgcn_mfma_f32_16x16x32_bf16(a1, b1, acc[1][1], 0, 0, 0);
        __syncthreads();
    }

#pragma unroll
    for (int c = 0; c < 2; c++) {
        int col = bn0 + wc * 32 + c * 16 + r;
        if (col >= Nn) continue;
#pragma unroll
        for (int i = 0; i < 2; i++) {
#pragma unroll
            for (int vv = 0; vv < 4; vv++) {
                int row = bm0 + wr * 32 + i * 16 + q * 4 + vv;
                if (row >= M) continue;
                if (om1) C16[(size_t)row * ldc + col] = f2bf(acc[i][c][vv]);
                else C16[(size_t)col * ldc + row * 20 + zz] = f2bf(acc[i][c][vv]);
            }
        }
    }
}

// ---------------- fused: t1 GEMM (blocks 0..767, FIRST) + GCN layer-1 GEMM (blocks 768..2047) ----------------
// t1: P[ks][1024][128] = A[1024,15000]fp32 @ Vt16^T (v4 full-line staged pipeline, R8/R10-verified)
// L1: h16 = relu(aggb @ W1t^T + b1), bf16 in/out, Nn=78 Npad=96 K=96, grid-equivalent (2,640)
// The two are data-independent; t1 blocks first so they start immediately.
#define T1LD 40
#define T1S  48
#define T1K  320
__global__ __launch_bounds__(256) void k_t1_l1(
    const float* __restrict__ t1A, const unsigned short* __restrict__ Bt, float* __restrict__ P,
    const unsigned short* __restrict__ A16, const unsigned short* __restrict__ W1t,
    const float* __restrict__ bias, unsigned short* __restrict__ C16) {
    __shared__ __align__(16) unsigned char smem[30720];
    int bx = blockIdx.x, tid = threadIdx.x;
    if (bx < 768) {
        unsigned short* AsS = (unsigned short*)smem;           // [2][64*40]  (buf*2560)
        unsigned short* BsS = (unsigned short*)smem + 5120;    // [2][128*40] (buf*5120)
        const int Klim = 15000;
        int mt = bx & 15, ks = bx >> 4;
        int bm0 = mt * 64;
        int k0 = ks * T1K;
        int w = tid >> 6, l = tid & 63, q = l >> 4, r = l & 15;
        int wr = w >> 1, wc = w & 1;

        floatx4 acc[2][4];
#pragma unroll
        for (int i = 0; i < 2; i++)
#pragma unroll
            for (int c = 0; c < 4; c++) acc[i][c] = (floatx4)0.0f;

        int ra = tid >> 3, ca = (tid & 7) * 4;
        int rb = tid >> 2, cb = (tid & 3) * 8;
        const float* Ap0 = t1A + (size_t)(bm0 + ra) * Klim + ca;
        const float* Ap1 = t1A + (size_t)(bm0 + ra + 32) * Klim + ca;
        const unsigned short* Bp0 = Bt + (size_t)rb * 15360 + cb;
        const unsigned short* Bp1 = Bt + (size_t)(rb + 64) * 15360 + cb;

        float4 aA0, aA1, aB0, aB1;
        short8 bA0, bA1, bB0, bB1;

        auto loadT = [&](int kt, float4& x0, float4& x1, short8& y0, short8& y1) {
            int c = kt + ca;
            if (c < Klim) {
                x0 = *(const float4*)(Ap0 + kt);
                x1 = *(const float4*)(Ap1 + kt);
            } else {
                x0 = make_float4(0.f, 0.f, 0.f, 0.f);
                x1 = make_float4(0.f, 0.f, 0.f, 0.f);
            }
            y0 = *(const short8*)(Bp0 + kt);
            y1 = *(const short8*)(Bp1 + kt);
        };
        auto stageW = [&](int buf, const float4& x0, const float4& x1, const short8& y0, const short8& y1) {
            short4v s0, s1;
            s0[0] = (short)f2bf(x0.x); s0[1] = (short)f2bf(x0.y); s0[2] = (short)f2bf(x0.z); s0[3] = (short)f2bf(x0.w);
            s1[0] = (short)f2bf(x1.x); s1[1] = (short)f2bf(x1.y); s1[2] = (short)f2bf(x1.z); s1[3] = (short)f2bf(x1.w);
            *(short4v*)&AsS[buf * 2560 + ra * T1LD + ca] = s0;
            *(short4v*)&AsS[buf * 2560 + (ra + 32) * T1LD + ca] = s1;
            *(short8*)&BsS[buf * 5120 + rb * T1LD + cb] = y0;
            *(short8*)&BsS[buf * 5120 + (rb + 64) * T1LD + cb] = y1;
        };
        auto compute = [&](int buf) {
            short8 a0 = *(const short8*)&AsS[buf * 2560 + (wr * 32 + r) * T1LD + q * 8];
            short8 a1 = *(const short8*)&AsS[buf * 2560 + (wr * 32 + 16 + r) * T1LD + q * 8];
            short8 b0 = *(const short8*)&BsS[buf * 5120 + (wc * 64 + r) * T1LD + q * 8];
            short8 b1 = *(const short8*)&BsS[buf * 5120 + (wc * 64 + 16 + r) * T1LD + q * 8];
            short8 b2 = *(const short8*)&BsS[buf * 5120 + (wc * 64 + 32 + r) * T1LD + q * 8];
            short8 b3 = *(const short8*)&BsS[buf * 5120 + (wc * 64 + 48 + r) * T1LD + q * 8];
            acc[0][0] = __builtin_amdgcn_mfma_f32_16x16x32_bf16(a0, b0, acc[0][0], 0, 0, 0);
            acc[0][1] = __builtin_amdgcn_mfma_f32_16x16x32_bf16(a0, b1, acc[0][1], 0, 0, 0);
            acc[0][2] = __builtin_amdgcn_mfma_f32_16x16x32_bf16(a0, b2, acc[0][2], 0, 0, 0);
            acc[0][3] = __builtin_amdgcn_mfma_f32_16x16x32_bf16(a0, b3, acc[0][3], 0, 0, 0);
            acc[1][0] = __builtin_amdgcn_mfma_f32_16x16x32_bf16(a1, b0, acc[1][0], 0, 0, 0);
            acc[1][1] = __builtin_amdgcn_mfma_f32_16x16x32_bf16(a1, b1, acc[1][1], 0, 0, 0);
            acc[1][2] = __builtin_amdgcn_mfma_f32_16x16x32_bf16(a1, b2, acc[1][2], 0, 0, 0);
            acc[1][3] = __builtin_amdgcn_mfma_f32_16x16x32_bf16(a1, b3, acc[1][3], 0, 0, 0);
        };

        loadT(k0, aA0, aA1, bA0, bA1);
        loadT(k0 + 32, aB0, aB1, bB0, bB1);
#pragma unroll
        for (int it = 0; it < T1K / 32; it += 2) {
            stageW(0, aA0, aA1, bA0, bA1);
            if (it + 2 < T1K / 32) loadT(k0 + (it + 2) * 32, aA0, aA1, bA0, bA1);
            asm volatile("s_waitcnt lgkmcnt(0)" ::: "memory");
            __builtin_amdgcn_s_barrier();
            asm volatile("" ::: "memory");
            compute(0);
            stageW(1, aB0, aB1, bB0, bB1);
            if (it + 3 < T1K / 32) loadT(k0 + (it + 3) * 32, aB0, aB1, bB0, bB1);
            asm volatile("s_waitcnt lgkmcnt(0)" ::: "memory");
            __builtin_amdgcn_s_barrier();
            asm volatile("" ::: "memory");
            compute(1);
        }

        float* Pp = P + (size_t)ks * (1024 * 128) + (size_t)bm0 * 128;
#pragma unroll
        for (int c = 0; c < 4; c++) {
            int col = wc * 64 + c * 16 + r;
#pragma unroll
            for (int i = 0; i < 2; i++) {
#pragma unroll
                for (int v = 0; v < 4; v++) {
                    int row = wr * 32 + i * 16 + q * 4 + v;
                    Pp[(size_t)row * 128 + col] = acc[i][c][v];
                }
            }
        }
    } else {
        // ---- GCN layer-1 GEMM: ABF16, bf16-out, relu; Nn=78, Npad=96, K=96, ld*=96 ----
        unsigned short* As = (unsigned short*)smem;          // 64*72
        unsigned short* Bs = (unsigned short*)smem + 4608;   // 64*72
        int v = bx - 768;
        int bn0 = (v & 1) * 64;
        int bm0 = (v >> 1) * 64;
        int w = tid >> 6, l = tid & 63, q = l >> 4, r = l & 15;
        int wr = w >> 1, wc = w & 1;

        floatx4 acc[2][2];
#pragma unroll
        for (int i = 0; i < 2; i++)
#pragma unroll
            for (int c = 0; c < 2; c++) acc[i][c] = (floatx4)0.0f;

        int mA = tid >> 2, kcA = (tid & 3) * 8;
        int gmA = bm0 + mA;
        int gnB = bn0 + mA;

        for (int kt = 0; kt < 96; kt += 32) {
            *(short8*)&As[mA * LDST + kcA] = *(const short8*)(A16 + (size_t)gmA * 96 + kt + kcA);
            *(short8*)&Bs[mA * LDST + kcA] = *(const short8*)(W1t + (size_t)gnB * 96 + kt + kcA);
            __syncthreads();
            short8 a0 = *(const short8*)&As[(wr * 32 + r) * LDST + q * 8];
            short8 a1 = *(const short8*)&As[(wr * 32 + 16 + r) * LDST + q * 8];
            short8 b0 = *(const short8*)&Bs[(wc * 32 + r) * LDST + q * 8];
            short8 b1 = *(const short8*)&Bs[(wc * 32 + 16 + r) * LDST + q * 8];
            acc[0][0] = __builtin_amdgcn_mfma_f32_16x16x32_bf16(a0, b0, acc[0][0], 0, 0, 0);
            acc[0][1] = __builtin_amdgcn_mfma_f32_16x16x32_bf16(a0, b1, acc[0][1], 0, 0, 0);
            acc[1][0] = __builtin_amdgcn_mfma_f32_16x16x32_bf16(a1, b0, acc[1][0], 0, 0, 0);
            acc[1][1] = __builtin_amdgcn_mfma_f32_16x16x32_bf16(a1, b1, acc[1][1], 0, 0, 0);
            __syncthreads();
        }

#pragma unroll
        for (int c2 = 0; c2 < 2; c2++) {
            int col = bn0 + wc * 32 + c2 * 16 + r;
            if (col >= 96) continue;
            bool live = col < 78;
            float bv = live ? bias[col] : 0.f;
#pragma unroll
            for (int i = 0; i < 2; i++) {
#pragma unroll
                for (int vv = 0; vv < 4; vv++) {
                    int row = bm0 + wr * 32 + i * 16 + q * 4 + vv;
                    float val = live ? fmaxf(acc[i][c2][vv] + bv, 0.f) : 0.f;
                    C16[(size_t)row * 96 + col] = live ? f2bf(val) : (unsigned short)0;
                }
            }
        }
    }
}

// ---------------- fused: u_gather (blocks 0..1023, FIRST) + agg16 F2=80 ----------------
__global__ __launch_bounds__(128) void k_agg16_ug(
    const unsigned* __restrict__ h, const float* __restrict__ dinv, const int* __restrict__ off,
    const int* __restrict__ srcs, unsigned* __restrict__ outb,
    const int* __restrict__ t2, const unsigned short* __restrict__ U,
    const float* __restrict__ b2v, float* __restrict__ xc) {
    __shared__ int offs[752];
    __shared__ float red[8][128];
    int bx = blockIdx.x, tid = threadIdx.x;
    if (bx < NB) {
        int b = bx;
        int rg = tid >> 4, lane = tid & 15;
        const int* t2b = t2 + (size_t)b * 750;
        for (int i = tid; i < 750; i += 128) offs[i] = i * 3328 + t2b[i] * 128;
        __syncthreads();
        float a[8] = {};
#pragma unroll 4
        for (int i = rg; i < 750; i += 8) {
            short8 v = *(const short8*)&U[(size_t)offs[i] + lane * 8];
#pragma unroll
            for (int c = 0; c < 8; c++) a[c] += bf2f((unsigned short)v[c]);
        }
#pragma unroll
        for (int c = 0; c < 8; c++) red[rg][lane * 8 + c] = a[c];
        __syncthreads();
        float s = b2v[tid];
#pragma unroll
        for (int g = 0; g < 8; g++) s += red[g][tid];
        xc[(size_t)b * 384 + 256 + tid] = s;
    } else {
        d_agg16_node(bx - NB, tid, h, dinv, off, srcs, outb, 80);
    }
}

// ---------------- fused: red_t1 (blocks 0..1023, FIRST) + segmax ----------------
__global__ void k_segmax_red(const unsigned short* __restrict__ h, unsigned short* __restrict__ g,
                             const float* __restrict__ P, float* __restrict__ xc) {
    int bx = blockIdx.x, tid = threadIdx.x;
    if (bx < NB) {
        if (tid < 128) {
            int row = bx, j = tid;
            const float* p = P + (size_t)row * 128 + j;
            float s = 0.f;
#pragma unroll
            for (int ks = 0; ks < T1S; ks++) s += p[(size_t)ks * (1024 * 128)];
            xc[(size_t)row * 384 + 128 + j] += s;
        }
    } else {
        int gr = bx - NB, f = tid;
        if (f >= 320) return;
        if (f >= 312) { g[(size_t)gr * 320 + f] = 0; return; }
        float m = 0.0f;
        const unsigned short* base = h + (size_t)gr * 40 * 312 + f;
        for (int i = 0; i < 40; i++) m = fmaxf(m, bf2f(base[(size_t)i * 312]));
        g[(size_t)gr * 320 + f] = f2bf(m);
    }
}

// out[b] = sum_j relu(f2[b,j]) * Wo[j] + bo
__global__ __launch_bounds__(64) void k_final(const float* __restrict__ f2, const float* __restrict__ Wo,
                                              const float* __restrict__ bo, float* __restrict__ out) {
    int b = blockIdx.x, lane = threadIdx.x;
    float s = 0.f;
    for (int j = lane; j < 512; j += 64) s += fmaxf(f2[(size_t)b * 512 + j], 0.f) * Wo[j];
    for (int off = 32; off; off >>= 1) s += __shfl_down(s, off);
    if (lane == 0) out[b] = s + bo[0];
}

extern "C" void kernel_launch(void* const* d_in, const int* in_sizes, int n_in,
                              void* d_out, int out_size, void* d_ws, size_t ws_size,
                              hipStream_t stream) {
    const float* x    = (const float*)d_in[0];
    const int*   ei   = (const int*)d_in[1];
    const float* t1   = (const float*)d_in[3];
    const int*   t2   = (const int*)d_in[4];
    const float* W1   = (const float*)d_in[5];
    const float* b1   = (const float*)d_in[6];
    const float* W2   = (const float*)d_in[7];
    const float* b2   = (const float*)d_in[8];
    const float* W3   = (const float*)d_in[9];
    const float* b3   = (const float*)d_in[10];
    const float* Wg1  = (const float*)d_in[11];
    const float* bg1  = (const float*)d_in[12];
    const float* Wg2  = (const float*)d_in[13];
    const float* bg2  = (const float*)d_in[14];
    const float* emb  = (const float*)d_in[15];
    const float* Wc2  = (const float*)d_in[16];
    const float* bc2  = (const float*)d_in[17];
    const float* Wxt2 = (const float*)d_in[18];
    const float* bxt2 = (const float*)d_in[19];
    const float* Wc1  = (const float*)d_in[20];
    const float* bc1  = (const float*)d_in[21];
    const float* Wxt1 = (const float*)d_in[22];
    const float* bxt1 = (const float*)d_in[23];
    const float* Wf1  = (const float*)d_in[24];
    const float* bf1  = (const float*)d_in[25];
    const float* Wf2  = (const float*)d_in[26];
    const float* bf2  = (const float*)d_in[27];
    const float* Wo   = (const float*)d_in[28];
    const float* bo   = (const float*)d_in[29];
    float* out = (float*)d_out;

    float* ws = (float*)d_ws;
    float* dinv  = ws + o_dinv;
    unsigned short* g312b = (unsigned short*)(ws + o_g312);   // 1024 x 320 bf16
    unsigned short* g1024b = (unsigned short*)(ws + o_g1024); // 1024 x 1024 bf16
    float* xc    = ws + o_xc;     // [1024 x 384] fp32
    unsigned short* f1b = (unsigned short*)(ws + o_f1);       // 1024 x 1024 bf16
    float* f2    = ws + o_f2;
    float* b1v   = ws + o_b1v;
    float* b2v   = ws + o_b2v;
    int* csrOff  = (int*)(ws + o_iws);
    int* csrCur  = csrOff + (NN + 1);
    int* csrSrc  = csrCur + NN;
    int* blockSum = (int*)(ws + o_f1 + 600000);  // scratch, dead before f1b written
    int* blockOff = blockSum + 40;
    float* bufA  = ws + o_bufA;
    float* bufB  = ws + o_bufB;
    float* T    = bufA;
    unsigned short* U16  = (unsigned short*)(bufA + 851968);
    unsigned short* Vt16 = (unsigned short*)(bufA + 2200000);  // 128 x 15360 bf16
    unsigned short* Wt   = (unsigned short*)(bufA + 3200000);  // transposed weights
    float* Wc2r = bufA + 4000000;
    float* Wc1r = bufA + 4200000;
    float* Btb  = bufA + 4400000;
    float* Pt1  = bufA + 6000000;  // t1 split-K partials (48*1024*128 fp32)
    // bf16 node pipeline (inside bufB)
    unsigned* aggb = (unsigned*)bufB;                          // NN*80 uints max
    unsigned short* h16 = (unsigned short*)(bufB + 5500000);   // up to NN*312

    unsigned short* W1t  = Wt + 0;
    unsigned short* W2t  = Wt + 12288;
    unsigned short* W3t  = Wt + 30720;
    unsigned short* Wg1t = Wt + 81920;
    unsigned short* Wg2t = Wt + 409600;
    unsigned short* Wf1t = Wt + 540672;
    unsigned short* Wf2t = Wt + 933888;

    // ---- memsets (no deps) + CSR build ----
    hipMemsetAsync(Vt16, 0, (size_t)128 * 15360 * 2, stream);
    hipMemsetAsync(b1v, 0, 256 * sizeof(float), stream);   // b1v+b2v contiguous; atomic bias folds need zero
    hipMemsetAsync(csrCur, 0, NN * sizeof(int), stream);
    k_hist<<<NE / 256, 256, 0, stream>>>(ei + NE, csrCur);
    k_scan1<<<40, 1024, 0, stream>>>(csrCur, csrOff, blockSum, dinv);
    k_scan2<<<1, 64, 0, stream>>>(blockSum, blockOff);
    k_scan3<<<40, 1024, 0, stream>>>(csrOff, csrCur, blockOff);

    // ---- all weight-only preprocessing in one launch ----
    k_prep_mega<<<7868, 256, 0, stream>>>(W1, W2, W3, Wg1, Wg2, Wf1, Wf2, Wt,
                                          Wc2, Wc1, Wc2r, Wc1r,
                                          Wxt1, Btb, bc1, bxt1, b1v,
                                          bc2, Wxt2, bxt2, b2v, emb, T);

    // ---- fused: CSR fill + both batched GEMMs + bias C-inits ----
    k_fbi<<<2768, 256, 0, stream>>>(ei, csrCur, csrSrc, Wc2r, T, Wc1r, Btb, U16, Vt16,
                                    xc, f2, bg2, b1v, bf2);

    // ---- agg_x standalone (full occupancy) ----
    k_agg_x<<<NN, 64, 0, stream>>>(x, dinv, csrOff, csrSrc, aggb);

    // ---- fused: t1 GEMM (768 blocks, first) + GCN layer-1 GEMM (1280 blocks) ----
    k_t1_l1<<<2048, 256, 0, stream>>>(t1, Vt16, Pt1, (const unsigned short*)aggb, W1t, b1, h16);

    // ---- GCN pipeline ----
    k_agg16<<<NN, 64, 0, stream>>>((unsigned*)h16, dinv, csrOff, csrSrc, aggb, 48);
    gemm_bt<true, true, false, true><<<dim3(3, 640, 1), 256, 0, stream>>>(
        aggb, W2t, b2, h16, 156, 160, 96, 96, 96, 96, 160, 96);
    // fused: u_gather (first 1024 blocks) + agg16 F2=80
    k_agg16_ug<<<NB + NN, 128, 0, stream>>>((unsigned*)h16, dinv, csrOff, csrSrc, aggb,
                                            t2, U16, b2v, xc);
    gemm_bt<true, true, false, true><<<dim3(5, 640, 1), 256, 0, stream>>>(
        aggb, W3t, b3, h16, 312, 312, 160, 160, 160, 160, 312, 160);
    // fused: red_t1 (first 1024 blocks) + segmax
    k_segmax_red<<<2 * NB, 320, 0, stream>>>(h16, g312b, Pt1, xc);
    gemm_bt<true, true, false, true><<<dim3(16, 16, 1), 256, 0, stream>>>(
        g312b, Wg1t, bg1, g1024b, 1024, 1024, 320, 320, 320, 320, 1024, 320);

    // xc[:,0:128] = g1024 @ Wg2 + bg2   (split-K atomic)
    gemm_bt<true, false, true, false><<<dim3(2, 16, 8), 256, 0, stream>>>(
        g1024b, Wg2t, nullptr, xc + 0, 128, 128, 1024, 1024, 1024, 1024, 384, 128);

    // ---- head ----
    gemm_bt<false, true, false, true><<<dim3(16, 16, 1), 256, 0, stream>>>(
        xc, Wf1t, bf1, f1b, 1024, 1024, 384, 384, 384, 384, 1024, 384);
    gemm_bt<true, false, true, false><<<dim3(8, 16, 4), 256, 0, stream>>>(
        f1b, Wf2t, nullptr, f2, 512, 512, 1024, 1024, 1024, 1024, 512, 256);
    k_final<<<NB, 64, 0, stream>>>(f2, Wo, bo, out);
}

// Round 12
// 419.859 us; speedup vs baseline: 1.1657x; 1.0083x over previous
//
#include <hip/hip_runtime.h>
#include <hip/hip_bf16.h>

// Problem constants
#define NN 40960      // nodes
#define NE 163840     // edges
#define NB 1024       // graphs

typedef __attribute__((ext_vector_type(8))) short short8;
typedef __attribute__((ext_vector_type(4))) short short4v;
typedef __attribute__((ext_vector_type(4))) float floatx4;

__device__ inline unsigned short f2bf(float f) {
    union { float f; unsigned u; } v; v.f = f;
    unsigned r = v.u + 0x7fffu + ((v.u >> 16) & 1u);
    return (unsigned short)(r >> 16);
}
__device__ inline float bf2f(unsigned short s) {
    union { unsigned u; float f; } v; v.u = ((unsigned)s) << 16; return v.f;
}
__device__ inline unsigned pack2bf(float lo, float hi) {
    return (unsigned)f2bf(lo) | ((unsigned)f2bf(hi) << 16);
}

// ---------------- workspace layout (float elements) ----------------
static const size_t o_dinv = 0, o_g312 = 40960, o_g1024 = 360448, o_xc = 1409024,
                    o_f1 = 1802240, o_f2 = 2850816, o_b1v = 3375104, o_b2v = 3375232,
                    o_iws = 3375360, o_bufA = 3621124, o_bufB = 16400644;
// bufA: T @0 | U16 @+851968 | Vt16 @+2200000 (128x15360 bf16) | Wt @+3200000
//       | Wc2r @+4000000 | Wc1r @+4200000 | Btb @+4400000 (ends 5.06M)
//       | Pt1 @+6000000 (48*1024*128 fp32, ends 12.3M < 12.78M)
// bufB: aggb @0 (NN*80 uints max) | h16 @5.5M

// ---------------- fused: edge histogram (blocks 0..639) + ALL weight preprocessing ----------------
// prep blocks (bp = bx-640):
//  [0,3328): weight transpose-convert -> Wt; [3328,4828): conv reshape; [4828,7388): Btb build
//  [7388,7452): bias folds (64 parallel, atomicAdd); [7452,7868): T build
// bp==0,tid==0 additionally zeroes the scan flag for k_scan_all.
__global__ __launch_bounds__(256) void k_histprep(
    const int* __restrict__ dst, int* __restrict__ cnt, int* __restrict__ flag,
    const float* __restrict__ W1, const float* __restrict__ W2, const float* __restrict__ W3,
    const float* __restrict__ Wg1, const float* __restrict__ Wg2, const float* __restrict__ Wf1,
    const float* __restrict__ Wf2, unsigned short* __restrict__ Wt,
    const float* __restrict__ Wc2, const float* __restrict__ Wc1,
    float* __restrict__ Wc2r, float* __restrict__ Wc1r,
    const float* __restrict__ Wxt1, float* __restrict__ Btb,
    const float* __restrict__ bc1, const float* __restrict__ bxt1, float* __restrict__ b1v,
    const float* __restrict__ bc2, const float* __restrict__ Wxt2, const float* __restrict__ bxt2,
    float* __restrict__ b2v,
    const float* __restrict__ emb, float* __restrict__ T) {
    __shared__ float el[128];
    int bx = blockIdx.x, tid = threadIdx.x;
    if (bx < 640) {
        int e = bx * 256 + tid;
        if (e < NE) atomicAdd(&cnt[dst[e]], 1);
        return;
    }
    int bp = bx - 640;
    if (bp == 0 && tid == 0) *flag = 0;   // visible to k_scan_all at next dispatch
    if (bp < 3328) {
        const int cum[8]  = {0, 128, 320, 640, 1664, 1792, 2816, 3328};
        const int KP[7]   = {96, 96, 160, 320, 1024, 384, 1024};
        const int KB[7]   = {78, 78, 156, 312, 1024, 384, 1024};
        const int NNm[7]  = {78, 156, 312, 1024, 128, 1024, 512};
        const size_t OFF[7] = {0, 12288, 30720, 81920, 409600, 540672, 933888};
        int m = 0;
        while (m < 6 && bp >= cum[m + 1]) m++;
        int r = bp - cum[m];
        const float* src = (m == 0) ? W1 : (m == 1) ? W2 : (m == 2) ? W3 : (m == 3) ? Wg1
                         : (m == 4) ? Wg2 : (m == 5) ? Wf1 : Wf2;
        int kp = KP[m], kb = KB[m], nn = NNm[m];
        unsigned short* d = Wt + OFF[m] + (size_t)r * kp;
        for (int k = tid; k < kp; k += 256) {
            float v = (r < nn && k < kb) ? src[(size_t)k * nn + r] : 0.f;
            d[k] = f2bf(v);
        }
    } else if (bp < 4828) {
        int cc = bp - 3328, j = tid;
        const float* W = (cc < 750) ? Wc2 : Wc1;
        float* Wr = (cc < 750) ? Wc2r : Wc1r;
        int c = (cc < 750) ? cc : cc - 750;
        Wr[(size_t)c * 256 + j] = W[(size_t)(j >> 3) * 6000 + c * 8 + (j & 7)];
    } else if (bp < 7388) {
        int idx = (bp - 4828) * 256 + tid;        // < 655360 = 20*256*128
        int j = idx & 127, ok = (idx >> 7) & 255, t = idx >> 15;
        int o = ok >> 3, k = ok & 7, lpos = t - k;
        float v = (lpos >= 0 && lpos < 13) ? Wxt1[(size_t)(o * 13 + lpos) * 128 + j] : 0.f;
        Btb[(size_t)(t * 256 + ok) * 128 + j] = v;
    } else if (bp < 7452) {
        if (tid >= 128) return;
        int b = bp - 7388, j = tid;
        if (b < 32) {
            const float* p = Wxt1 + (size_t)b * 13 * 128 + j;
            float t = 0.f;
            for (int l = 0; l < 13; l++) t += p[(size_t)l * 128];
            float add = bc1[b] * t + ((b == 0) ? bxt1[j] : 0.f);
            atomicAdd(&b1v[j], add);
        } else {
            int o = b - 32;
            const float* p = Wxt2 + (size_t)o * 121 * 128 + j;
            float t = 0.f;
            for (int l = 0; l < 121; l++) t += p[(size_t)l * 128];
            float add = bc2[o] * t + ((o == 0) ? bxt2[j] : 0.f);
            atomicAdd(&b2v[j], add);
        }
    } else {
        int tb = bp - 7452;                       // < 416 = 26*16
        int v = tb >> 4, op = tb & 15;
        int o = op * 2 + (tid >> 7), j = tid & 127;
        if (tid < 128) el[j] = emb[(size_t)v * 128 + j];
        __syncthreads();
        float acc[8] = {};
        for (int l = 0; l < 121; l++) {
            float w = Wxt2[(size_t)(o * 121 + l) * 128 + j];
#pragma unroll
            for (int k = 0; k < 8; k++) acc[k] += el[l + k] * w;
        }
#pragma unroll
        for (int k = 0; k < 8; k++) T[(size_t)(v * 256 + o * 8 + k) * 128 + j] = acc[k];
    }
}

// ---------------- single-launch exclusive scan over 40960 counts (40 co-resident blocks) ----------------
// Device-scope atomic flag barrier: all 40 blocks are trivially co-resident (<< 256 CUs), so the
// spin is deadlock-free. blockSum publish/read via atomics (cross-XCD coherent). Local exclusive
// prefix kept in registers (no offTmp round-trip).
__global__ __launch_bounds__(1024) void k_scan_all(const int* __restrict__ cnt, int* __restrict__ off,
                                                   int* __restrict__ cur, float* __restrict__ dinv,
                                                   int* __restrict__ blockSum, int* __restrict__ flag) {
    __shared__ int lds[1024];
    __shared__ int bs[40];
    int tid = threadIdx.x, bx = blockIdx.x;
    int i = bx * 1024 + tid;
    int v = cnt[i];
    dinv[i] = rsqrtf((float)v + 1.0f);  // deg = in-count + self loop
    lds[tid] = v;
    __syncthreads();
    for (int s = 1; s < 1024; s <<= 1) {
        int t = (tid >= s) ? lds[tid - s] : 0;
        __syncthreads();
        lds[tid] += t;
        __syncthreads();
    }
    int localExcl = lds[tid] - v;
    if (tid == 1023) {
        atomicExch(&blockSum[bx], lds[1023]);   // publish (coherent)
        __threadfence();
        atomicAdd(flag, 1);                     // release
    }
    if (tid == 0) {
        while (atomicAdd(flag, 0) < 40) { }     // acquire spin (co-resident, safe)
    }
    __syncthreads();
    if (tid < 40) bs[tid] = atomicAdd(&blockSum[tid], 0);  // coherent read
    __syncthreads();
    int pref = 0;
    for (int j = 0; j < bx; j++) pref += bs[j];
    int o = localExcl + pref;
    off[i] = o;
    cur[i] = o;
    if (i == NN - 1) off[NN] = NE;
}

// ---------------- GCN aggregation, layer 1: fp32 x in, bf16 out padded to 96 (standalone, full occ) ----
__global__ __launch_bounds__(64) void k_agg_x(const float* __restrict__ x, const float* __restrict__ dinv,
                                              const int* __restrict__ off, const int* __restrict__ srcs,
                                              unsigned* __restrict__ out) {
    int n = blockIdx.x;
    int f = threadIdx.x;          // uint column (2 floats)
    if (f >= 48) return;
    if (f >= 39) { out[(size_t)n * 48 + f] = 0; return; }
    float di = dinv[n];
    float2 sv = *(const float2*)&x[(size_t)n * 78 + 2 * f];
    float a0 = sv.x * di * di, a1 = sv.y * di * di;
    int e0 = off[n], e1 = off[n + 1];
    int e = e0;
    for (; e + 4 <= e1; e += 4) {
        int s0 = srcs[e], s1 = srcs[e + 1], s2 = srcs[e + 2], s3 = srcs[e + 3];
        float d0 = dinv[s0] * di, d1 = dinv[s1] * di, d2 = dinv[s2] * di, d3 = dinv[s3] * di;
        float2 v0 = *(const float2*)&x[(size_t)s0 * 78 + 2 * f];
        float2 v1 = *(const float2*)&x[(size_t)s1 * 78 + 2 * f];
        float2 v2 = *(const float2*)&x[(size_t)s2 * 78 + 2 * f];
        float2 v3 = *(const float2*)&x[(size_t)s3 * 78 + 2 * f];
        a0 += v0.x * d0 + v1.x * d1 + v2.x * d2 + v3.x * d3;
        a1 += v0.y * d0 + v1.y * d1 + v2.y * d2 + v3.y * d3;
    }
    for (; e < e1; e++) {
        int s = srcs[e];
        float dd = dinv[s] * di;
        float2 v = *(const float2*)&x[(size_t)s * 78 + 2 * f];
        a0 += v.x * dd; a1 += v.y * dd;
    }
    out[(size_t)n * 48 + f] = pack2bf(a0, a1);
}

// ---------------- GCN aggregation bf16 in/out helper ----------------
__device__ inline void d_agg16_node(int n, int f, const unsigned* __restrict__ h,
                                    const float* __restrict__ dinv, const int* __restrict__ off,
                                    const int* __restrict__ srcs, unsigned* __restrict__ out, int F2) {
    if (f >= F2) return;
    float di = dinv[n];
    unsigned s0v = h[(size_t)n * F2 + f];
    float a0 = bf2f((unsigned short)(s0v & 0xffff)) * di * di;
    float a1 = bf2f((unsigned short)(s0v >> 16)) * di * di;
    int e0 = off[n], e1 = off[n + 1];
    int e = e0;
    for (; e + 4 <= e1; e += 4) {
        int s0 = srcs[e], s1 = srcs[e + 1], s2 = srcs[e + 2], s3 = srcs[e + 3];
        float d0 = dinv[s0] * di, d1 = dinv[s1] * di, d2 = dinv[s2] * di, d3 = dinv[s3] * di;
        unsigned v0 = h[(size_t)s0 * F2 + f];
        unsigned v1 = h[(size_t)s1 * F2 + f];
        unsigned v2 = h[(size_t)s2 * F2 + f];
        unsigned v3 = h[(size_t)s3 * F2 + f];
        a0 += bf2f((unsigned short)(v0 & 0xffff)) * d0 + bf2f((unsigned short)(v1 & 0xffff)) * d1
            + bf2f((unsigned short)(v2 & 0xffff)) * d2 + bf2f((unsigned short)(v3 & 0xffff)) * d3;
        a1 += bf2f((unsigned short)(v0 >> 16)) * d0 + bf2f((unsigned short)(v1 >> 16)) * d1
            + bf2f((unsigned short)(v2 >> 16)) * d2 + bf2f((unsigned short)(v3 >> 16)) * d3;
    }
    for (; e < e1; e++) {
        int s = srcs[e];
        float dd = dinv[s] * di;
        unsigned v = h[(size_t)s * F2 + f];
        a0 += bf2f((unsigned short)(v & 0xffff)) * dd;
        a1 += bf2f((unsigned short)(v >> 16)) * dd;
    }
    out[(size_t)n * F2 + f] = pack2bf(a0, a1);
}

// standalone agg16 (layer-2 input, F2=48)
__global__ void k_agg16(const unsigned* __restrict__ h, const float* __restrict__ dinv,
                        const int* __restrict__ off, const int* __restrict__ srcs,
                        unsigned* __restrict__ out, int F2) {
    d_agg16_node(blockIdx.x, threadIdx.x, h, dinv, off, srcs, out, F2);
}

// ---------------- bf16 MFMA GEMM with transposed-bf16 B: C = A @ Bt^T ----------------
#define LDST 72
template <bool ABF16, bool OUTBF16, bool ATOMIC, bool RELU_OUT>
__global__ __launch_bounds__(256) void gemm_bt(const void* __restrict__ Av, const unsigned short* __restrict__ Bt,
                                               const float* __restrict__ bias, void* __restrict__ Cv,
                                               int Nn, int Npad, int Kpad, int Klim,
                                               int lda, int ldb, int ldc, int ksplit) {
    __shared__ __align__(16) unsigned short As[64 * LDST];
    __shared__ __align__(16) unsigned short Bs[64 * LDST];
    const float* Af = (const float*)Av;
    const unsigned short* A16 = (const unsigned short*)Av;
    float* Cf = (float*)Cv;
    unsigned short* C16 = (unsigned short*)Cv;
    int bn0 = blockIdx.x * 64;
    int bm0 = blockIdx.y * 64;
    int k0 = blockIdx.z * ksplit;
    int kend = k0 + ksplit; if (kend > Kpad) kend = Kpad;
    int tid = threadIdx.x;
    int w = tid >> 6, l = tid & 63, q = l >> 4, r = l & 15;
    int wr = w >> 1, wc = w & 1;

    floatx4 acc[2][2];
#pragma unroll
    for (int i = 0; i < 2; i++)
#pragma unroll
        for (int c = 0; c < 2; c++) acc[i][c] = (floatx4)0.0f;

    int mA = tid >> 2, kcA = (tid & 3) * 8;
    int nB = tid >> 2, kcB = (tid & 3) * 8;
    int gmA = bm0 + mA;
    int gnB = bn0 + nB;

    for (int kt = k0; kt < kend; kt += 32) {
        if (ABF16) {
            *(short8*)&As[mA * LDST + kcA] = *(const short8*)(A16 + (size_t)gmA * lda + kt + kcA);
        } else {
            const float* Ap = Af + (size_t)gmA * lda + kt + kcA;
            float av[8];
            if (kt + kcA + 8 <= Klim) {
#pragma unroll
                for (int j = 0; j < 4; j++) {
                    float2 p = *(const float2*)(Ap + j * 2);
                    av[j * 2] = p.x; av[j * 2 + 1] = p.y;
                }
            } else {
#pragma unroll
                for (int j = 0; j < 8; j++) av[j] = (kt + kcA + j < Klim) ? Ap[j] : 0.f;
            }
            short8 sv;
#pragma unroll
            for (int j = 0; j < 8; j++) sv[j] = (short)f2bf(av[j]);
            *(short8*)&As[mA * LDST + kcA] = sv;
        }
        *(short8*)&Bs[nB * LDST + kcB] = *(const short8*)(Bt + (size_t)gnB * ldb + kt + kcB);
        __syncthreads();
        short8 a0 = *(const short8*)&As[(wr * 32 + r) * LDST + q * 8];
        short8 a1 = *(const short8*)&As[(wr * 32 + 16 + r) * LDST + q * 8];
        short8 b0 = *(const short8*)&Bs[(wc * 32 + r) * LDST + q * 8];
        short8 b1 = *(const short8*)&Bs[(wc * 32 + 16 + r) * LDST + q * 8];
        acc[0][0] = __builtin_amdgcn_mfma_f32_16x16x32_bf16(a0, b0, acc[0][0], 0, 0, 0);
        acc[0][1] = __builtin_amdgcn_mfma_f32_16x16x32_bf16(a0, b1, acc[0][1], 0, 0, 0);
        acc[1][0] = __builtin_amdgcn_mfma_f32_16x16x32_bf16(a1, b0, acc[1][0], 0, 0, 0);
        acc[1][1] = __builtin_amdgcn_mfma_f32_16x16x32_bf16(a1, b1, acc[1][1], 0, 0, 0);
        __syncthreads();
    }

#pragma unroll
    for (int c2 = 0; c2 < 2; c2++) {
        int col = bn0 + wc * 32 + c2 * 16 + r;
        if (col >= Npad) continue;
        bool live = col < Nn;
        float bv = (bias && live) ? bias[col] : 0.f;
#pragma unroll
        for (int i = 0; i < 2; i++) {
#pragma unroll
            for (int v = 0; v < 4; v++) {
                int row = bm0 + wr * 32 + i * 16 + q * 4 + v;
                float val = live ? (acc[i][c2][v] + bv) : 0.f;
                if (RELU_OUT) val = fmaxf(val, 0.f);
                if (OUTBF16) {
                    C16[(size_t)row * ldc + col] = live ? f2bf(val) : (unsigned short)0;
                } else if (live) {
                    if (ATOMIC) atomicAdd(&Cf[(size_t)row * ldc + col], val);
                    else Cf[(size_t)row * ldc + col] = val;
                }
            }
        }
    }
}

// ---------------- fused: k_fill + batch_both + initC (mutually independent) ----------------
// blocks [0,640): CSR fill; [640,1744): batched GEMMs (z<26->U16, z>=26->Vt16); [1744,2768): initC
__global__ __launch_bounds__(256) void k_fbi(
    const int* __restrict__ ei, int* __restrict__ cur, int* __restrict__ srcOut,
    const float* __restrict__ Wc2r, const float* __restrict__ T,
    const float* __restrict__ Wc1r, const float* __restrict__ Btb,
    unsigned short* __restrict__ U16, unsigned short* __restrict__ Vt16,
    float* __restrict__ xc, float* __restrict__ f2,
    const float* __restrict__ bg2, const float* __restrict__ b1v, const float* __restrict__ bf2) {
    __shared__ __align__(16) unsigned short As[64 * LDST];
    __shared__ __align__(16) unsigned short Bs[64 * LDST];
    int bx = blockIdx.x, tid = threadIdx.x;
    if (bx < 640) {
        int e = bx * 256 + tid;
        if (e >= NE) return;
        int s = ei[e], d = ei[NE + e];
        int pos = atomicAdd(&cur[d], 1);
        srcOut[pos] = s;
        return;
    }
    if (bx >= 1744) {
        int b = bx - 1744;
        for (int t = tid; t < 768; t += 256) {
            if (t < 128) xc[(size_t)b * 384 + t] = bg2[t];
            else if (t < 256) xc[(size_t)b * 384 + t] = b1v[t - 128];
            else f2[(size_t)b * 512 + t - 256] = bf2[t - 256];
        }
        return;
    }
    // ---- batch_both: v = bx-640 -> (gx, gy, gz) of dim3(2,12,46) ----
    int v = bx - 640;
    int gx = v & 1, gy = (v >> 1) % 12, gz = (v >> 1) / 12;
    const int M = 750, Nn = 128, K = 256;
    bool om1 = gz < 26;
    const float* A = om1 ? Wc2r : Wc1r;
    const float* Bm = om1 ? (T + (size_t)gz * 32768) : (Btb + (size_t)(gz - 26) * 32768);
    unsigned short* C16 = om1 ? (U16 + (size_t)gz * 128) : Vt16;
    int ldc = om1 ? 3328 : 15360;
    int zz = gz - 26;
    int bn0 = gx * 64;
    int bm0 = gy * 64;
    int w = tid >> 6, l = tid & 63, q = l >> 4, r = l & 15;
    int wr = w >> 1, wc = w & 1;

    floatx4 acc[2][2];
#pragma unroll
    for (int i = 0; i < 2; i++)
#pragma unroll
        for (int c = 0; c < 2; c++) acc[i][c] = (floatx4)0.0f;

    int mA = tid >> 2, kcA = (tid & 3) * 8;
    int nB = tid >> 2, kcB = (tid & 3) * 8;
    int gmA = bm0 + mA;
    int gnB = bn0 + nB;

    for (int kt = 0; kt < K; kt += 32) {
        {
            float av[8];
            const float* Ap = A + (size_t)gmA * K + kt + kcA;
            if (gmA < M) {
#pragma unroll
                for (int j = 0; j < 4; j++) {
                    float2 p = *(const float2*)(Ap + j * 2);
                    av[j * 2] = p.x; av[j * 2 + 1] = p.y;
                }
            } else {
#pragma unroll
                for (int j = 0; j < 8; j++) av[j] = 0.f;
            }
            short8 sv;
#pragma unroll
            for (int j = 0; j < 8; j++) sv[j] = (short)f2bf(av[j]);
            *(short8*)&As[mA * LDST + kcA] = sv;
        }
        {
            short8 sv;
#pragma unroll
            for (int j = 0; j < 8; j++) {
                int gk = kt + kcB + j;
                float vv = (gnB < Nn) ? Bm[(size_t)gk * Nn + gnB] : 0.f;
                sv[j] = (short)f2bf(vv);
            }
            *(short8*)&Bs[nB * LDST + kcB] = sv;
        }
        __syncthreads();
        short8 a0 = *(const short8*)&As[(wr * 32 + r) * LDST + q * 8];
        short8 a1 = *(const short8*)&As[(wr * 32 + 16 + r) * LDST + q * 8];
        short8 b0 = *(const short8*)&Bs[(wc * 32 + r) * LDST + q * 8];
        short8 b1 = *(const short8*)&Bs[(wc * 32 + 16 + r) * LDST + q * 8];
        acc[0][0] = __builtin_amdgcn_mfma_f32_16x16x32_bf16(a0, b0, acc[0][0], 0, 0, 0);
        acc[0][1] = __builtin_amdgcn_mfma_f32_16x16x32_bf16(a0, b1, acc[0][1], 0, 0, 0);
        acc[1][0] = __builtin_amdgcn_mfma_f32_16x16x32_bf16(a1, b0, acc[1][0], 0, 0, 0);
        acc[1][1] = __builtin_amdgcn_mfma_f32_16x16x32_bf16(a1, b1, acc[1][1], 0, 0, 0);
        __syncthreads();
    }

#pragma unroll
    for (int c = 0; c < 2; c++) {
        int col = bn0 + wc * 32 + c * 16 + r;
        if (col >= Nn) continue;
#pragma unroll
        for (int i = 0; i < 2; i++) {
#pragma unroll
            for (int vv = 0; vv < 4; vv++) {
                int row = bm0 + wr * 32 + i * 16 + q * 4 + vv;
                if (row >= M) continue;
                if (om1) C16[(size_t)row * ldc + col] = f2bf(acc[i][c][vv]);
                else C16[(size_t)col * ldc + row * 20 + zz] = f2bf(acc[i][c][vv]);
            }
        }
    }
}

// ---------------- fused: t1 GEMM (blocks 0..767, FIRST) + GCN layer-1 GEMM (blocks 768..2047) ----------------
#define T1LD 40
#define T1S  48
#define T1K  320
__global__ __launch_bounds__(256) void k_t1_l1(
    const float* __restrict__ t1A, const unsigned short* __restrict__ Bt, float* __restrict__ P,
    const unsigned short* __restrict__ A16, const unsigned short* __restrict__ W1t,
    const float* __restrict__ bias, unsigned short* __restrict__ C16) {
    __shared__ __align__(16) unsigned char smem[30720];
    int bx = blockIdx.x, tid = threadIdx.x;
    if (bx < 768) {
        unsigned short* AsS = (unsigned short*)smem;           // [2][64*40]  (buf*2560)
        unsigned short* BsS = (unsigned short*)smem + 5120;    // [2][128*40] (buf*5120)
        const int Klim = 15000;
        int mt = bx & 15, ks = bx >> 4;
        int bm0 = mt * 64;
        int k0 = ks * T1K;
        int w = tid >> 6, l = tid & 63, q = l >> 4, r = l & 15;
        int wr = w >> 1, wc = w & 1;

        floatx4 acc[2][4];
#pragma unroll
        for (int i = 0; i < 2; i++)
#pragma unroll
            for (int c = 0; c < 4; c++) acc[i][c] = (floatx4)0.0f;

        int ra = tid >> 3, ca = (tid & 7) * 4;
        int rb = tid >> 2, cb = (tid & 3) * 8;
        const float* Ap0 = t1A + (size_t)(bm0 + ra) * Klim + ca;
        const float* Ap1 = t1A + (size_t)(bm0 + ra + 32) * Klim + ca;
        const unsigned short* Bp0 = Bt + (size_t)rb * 15360 + cb;
        const unsigned short* Bp1 = Bt + (size_t)(rb + 64) * 15360 + cb;

        float4 aA0, aA1, aB0, aB1;
        short8 bA0, bA1, bB0, bB1;

        auto loadT = [&](int kt, float4& x0, float4& x1, short8& y0, short8& y1) {
            int c = kt + ca;
            if (c < Klim) {
                x0 = *(const float4*)(Ap0 + kt);
                x1 = *(const float4*)(Ap1 + kt);
            } else {
                x0 = make_float4(0.f, 0.f, 0.f, 0.f);
                x1 = make_float4(0.f, 0.f, 0.f, 0.f);
            }
            y0 = *(const short8*)(Bp0 + kt);
            y1 = *(const short8*)(Bp1 + kt);
        };
        auto stageW = [&](int buf, const float4& x0, const float4& x1, const short8& y0, const short8& y1) {
            short4v s0, s1;
            s0[0] = (short)f2bf(x0.x); s0[1] = (short)f2bf(x0.y); s0[2] = (short)f2bf(x0.z); s0[3] = (short)f2bf(x0.w);
            s1[0] = (short)f2bf(x1.x); s1[1] = (short)f2bf(x1.y); s1[2] = (short)f2bf(x1.z); s1[3] = (short)f2bf(x1.w);
            *(short4v*)&AsS[buf * 2560 + ra * T1LD + ca] = s0;
            *(short4v*)&AsS[buf * 2560 + (ra + 32) * T1LD + ca] = s1;
            *(short8*)&BsS[buf * 5120 + rb * T1LD + cb] = y0;
            *(short8*)&BsS[buf * 5120 + (rb + 64) * T1LD + cb] = y1;
        };
        auto compute = [&](int buf) {
            short8 a0 = *(const short8*)&AsS[buf * 2560 + (wr * 32 + r) * T1LD + q * 8];
            short8 a1 = *(const short8*)&AsS[buf * 2560 + (wr * 32 + 16 + r) * T1LD + q * 8];
            short8 b0 = *(const short8*)&BsS[buf * 5120 + (wc * 64 + r) * T1LD + q * 8];
            short8 b1 = *(const short8*)&BsS[buf * 5120 + (wc * 64 + 16 + r) * T1LD + q * 8];
            short8 b2 = *(const short8*)&BsS[buf * 5120 + (wc * 64 + 32 + r) * T1LD + q * 8];
            short8 b3 = *(const short8*)&BsS[buf * 5120 + (wc * 64 + 48 + r) * T1LD + q * 8];
            acc[0][0] = __builtin_amdgcn_mfma_f32_16x16x32_bf16(a0, b0, acc[0][0], 0, 0, 0);
            acc[0][1] = __builtin_amdgcn_mfma_f32_16x16x32_bf16(a0, b1, acc[0][1], 0, 0, 0);
            acc[0][2] = __builtin_amdgcn_mfma_f32_16x16x32_bf16(a0, b2, acc[0][2], 0, 0, 0);
            acc[0][3] = __builtin_amdgcn_mfma_f32_16x16x32_bf16(a0, b3, acc[0][3], 0, 0, 0);
            acc[1][0] = __builtin_amdgcn_mfma_f32_16x16x32_bf16(a1, b0, acc[1][0], 0, 0, 0);
            acc[1][1] = __builtin_amdgcn_mfma_f32_16x16x32_bf16(a1, b1, acc[1][1], 0, 0, 0);
            acc[1][2] = __builtin_amdgcn_mfma_f32_16x16x32_bf16(a1, b2, acc[1][2], 0, 0, 0);
            acc[1][3] = __builtin_amdgcn_mfma_f32_16x16x32_bf16(a1, b3, acc[1][3], 0, 0, 0);
        };

        loadT(k0, aA0, aA1, bA0, bA1);
        loadT(k0 + 32, aB0, aB1, bB0, bB1);
#pragma unroll
        for (int it = 0; it < T1K / 32; it += 2) {
            stageW(0, aA0, aA1, bA0, bA1);
            if (it + 2 < T1K / 32) loadT(k0 + (it + 2) * 32, aA0, aA1, bA0, bA1);
            asm volatile("s_waitcnt lgkmcnt(0)" ::: "memory");
            __builtin_amdgcn_s_barrier();
            asm volatile("" ::: "memory");
            compute(0);
            stageW(1, aB0, aB1, bB0, bB1);
            if (it + 3 < T1K / 32) loadT(k0 + (it + 3) * 32, aB0, aB1, bB0, bB1);
            asm volatile("s_waitcnt lgkmcnt(0)" ::: "memory");
            __builtin_amdgcn_s_barrier();
            asm volatile("" ::: "memory");
            compute(1);
        }

        float* Pp = P + (size_t)ks * (1024 * 128) + (size_t)bm0 * 128;
#pragma unroll
        for (int c = 0; c < 4; c++) {
            int col = wc * 64 + c * 16 + r;
#pragma unroll
            for (int i = 0; i < 2; i++) {
#pragma unroll
                for (int v = 0; v < 4; v++) {
                    int row = wr * 32 + i * 16 + q * 4 + v;
                    Pp[(size_t)row * 128 + col] = acc[i][c][v];
                }
            }
        }
    } else {
        // ---- GCN layer-1 GEMM: ABF16, bf16-out, relu; Nn=78, Npad=96, K=96, ld*=96 ----
        unsigned short* As = (unsigned short*)smem;          // 64*72
        unsigned short* Bs = (unsigned short*)smem + 4608;   // 64*72
        int v = bx - 768;
        int bn0 = (v & 1) * 64;
        int bm0 = (v >> 1) * 64;
        int w = tid >> 6, l = tid & 63, q = l >> 4, r = l & 15;
        int wr = w >> 1, wc = w & 1;

        floatx4 acc[2][2];
#pragma unroll
        for (int i = 0; i < 2; i++)
#pragma unroll
            for (int c = 0; c < 2; c++) acc[i][c] = (floatx4)0.0f;

        int mA = tid >> 2, kcA = (tid & 3) * 8;
        int gmA = bm0 + mA;
        int gnB = bn0 + mA;

        for (int kt = 0; kt < 96; kt += 32) {
            *(short8*)&As[mA * LDST + kcA] = *(const short8*)(A16 + (size_t)gmA * 96 + kt + kcA);
            *(short8*)&Bs[mA * LDST + kcA] = *(const short8*)(W1t + (size_t)gnB * 96 + kt + kcA);
            __syncthreads();
            short8 a0 = *(const short8*)&As[(wr * 32 + r) * LDST + q * 8];
            short8 a1 = *(const short8*)&As[(wr * 32 + 16 + r) * LDST + q * 8];
            short8 b0 = *(const short8*)&Bs[(wc * 32 + r) * LDST + q * 8];
            short8 b1 = *(const short8*)&Bs[(wc * 32 + 16 + r) * LDST + q * 8];
            acc[0][0] = __builtin_amdgcn_mfma_f32_16x16x32_bf16(a0, b0, acc[0][0], 0, 0, 0);
            acc[0][1] = __builtin_amdgcn_mfma_f32_16x16x32_bf16(a0, b1, acc[0][1], 0, 0, 0);
            acc[1][0] = __builtin_amdgcn_mfma_f32_16x16x32_bf16(a1, b0, acc[1][0], 0, 0, 0);
            acc[1][1] = __builtin_amdgcn_mfma_f32_16x16x32_bf16(a1, b1, acc[1][1], 0, 0, 0);
            __syncthreads();
        }

#pragma unroll
        for (int c2 = 0; c2 < 2; c2++) {
            int col = bn0 + wc * 32 + c2 * 16 + r;
            if (col >= 96) continue;
            bool live = col < 78;
            float bv = live ? bias[col] : 0.f;
#pragma unroll
            for (int i = 0; i < 2; i++) {
#pragma unroll
                for (int vv = 0; vv < 4; vv++) {
                    int row = bm0 + wr * 32 + i * 16 + q * 4 + vv;
                    float val = live ? fmaxf(acc[i][c2][vv] + bv, 0.f) : 0.f;
                    C16[(size_t)row * 96 + col] = live ? f2bf(val) : (unsigned short)0;
                }
            }
        }
    }
}

// ---------------- fused: u_gather (blocks 0..1023, FIRST) + agg16 F2=80 ----------------
__global__ __launch_bounds__(128) void k_agg16_ug(
    const unsigned* __restrict__ h, const float* __restrict__ dinv, const int* __restrict__ off,
    const int* __restrict__ srcs, unsigned* __restrict__ outb,
    const int* __restrict__ t2, const unsigned short* __restrict__ U,
    const float* __restrict__ b2v, float* __restrict__ xc) {
    __shared__ int offs[752];
    __shared__ float red[8][128];
    int bx = blockIdx.x, tid = threadIdx.x;
    if (bx < NB) {
        int b = bx;
        int rg = tid >> 4, lane = tid & 15;
        const int* t2b = t2 + (size_t)b * 750;
        for (int i = tid; i < 750; i += 128) offs[i] = i * 3328 + t2b[i] * 128;
        __syncthreads();
        float a[8] = {};
#pragma unroll 4
        for (int i = rg; i < 750; i += 8) {
            short8 v = *(const short8*)&U[(size_t)offs[i] + lane * 8];
#pragma unroll
            for (int c = 0; c < 8; c++) a[c] += bf2f((unsigned short)v[c]);
        }
#pragma unroll
        for (int c = 0; c < 8; c++) red[rg][lane * 8 + c] = a[c];
        __syncthreads();
        float s = b2v[tid];
#pragma unroll
        for (int g = 0; g < 8; g++) s += red[g][tid];
        xc[(size_t)b * 384 + 256 + tid] = s;
    } else {
        d_agg16_node(bx - NB, tid, h, dinv, off, srcs, outb, 80);
    }
}

// ---------------- fused: red_t1 (blocks 0..1023, FIRST) + segmax ----------------
__global__ void k_segmax_red(const unsigned short* __restrict__ h, unsigned short* __restrict__ g,
                             const float* __restrict__ P, float* __restrict__ xc) {
    int bx = blockIdx.x, tid = threadIdx.x;
    if (bx < NB) {
        if (tid < 128) {
            int row = bx, j = tid;
            const float* p = P + (size_t)row * 128 + j;
            float s = 0.f;
#pragma unroll
            for (int ks = 0; ks < T1S; ks++) s += p[(size_t)ks * (1024 * 128)];
            xc[(size_t)row * 384 + 128 + j] += s;
        }
    } else {
        int gr = bx - NB, f = tid;
        if (f >= 320) return;
        if (f >= 312) { g[(size_t)gr * 320 + f] = 0; return; }
        float m = 0.0f;
        const unsigned short* base = h + (size_t)gr * 40 * 312 + f;
        for (int i = 0; i < 40; i++) m = fmaxf(m, bf2f(base[(size_t)i * 312]));
        g[(size_t)gr * 320 + f] = f2bf(m);
    }
}

// out[b] = sum_j relu(f2[b,j]) * Wo[j] + bo
__global__ __launch_bounds__(64) void k_final(const float* __restrict__ f2, const float* __restrict__ Wo,
                                              const float* __restrict__ bo, float* __restrict__ out) {
    int b = blockIdx.x, lane = threadIdx.x;
    float s = 0.f;
    for (int j = lane; j < 512; j += 64) s += fmaxf(f2[(size_t)b * 512 + j], 0.f) * Wo[j];
    for (int off = 32; off; off >>= 1) s += __shfl_down(s, off);
    if (lane == 0) out[b] = s + bo[0];
}

extern "C" void kernel_launch(void* const* d_in, const int* in_sizes, int n_in,
                              void* d_out, int out_size, void* d_ws, size_t ws_size,
                              hipStream_t stream) {
    const float* x    = (const float*)d_in[0];
    const int*   ei   = (const int*)d_in[1];
    const float* t1   = (const float*)d_in[3];
    const int*   t2   = (const int*)d_in[4];
    const float* W1   = (const float*)d_in[5];
    const float* b1   = (const float*)d_in[6];
    const float* W2   = (const float*)d_in[7];
    const float* b2   = (const float*)d_in[8];
    const float* W3   = (const float*)d_in[9];
    const float* b3   = (const float*)d_in[10];
    const float* Wg1  = (const float*)d_in[11];
    const float* bg1  = (const float*)d_in[12];
    const float* Wg2  = (const float*)d_in[13];
    const float* bg2  = (const float*)d_in[14];
    const float* emb  = (const float*)d_in[15];
    const float* Wc2  = (const float*)d_in[16];
    const float* bc2  = (const float*)d_in[17];
    const float* Wxt2 = (const float*)d_in[18];
    const float* bxt2 = (const float*)d_in[19];
    const float* Wc1  = (const float*)d_in[20];
    const float* bc1  = (const float*)d_in[21];
    const float* Wxt1 = (const float*)d_in[22];
    const float* bxt1 = (const float*)d_in[23];
    const float* Wf1  = (const float*)d_in[24];
    const float* bf1  = (const float*)d_in[25];
    const float* Wf2  = (const float*)d_in[26];
    const float* bf2  = (const float*)d_in[27];
    const float* Wo   = (const float*)d_in[28];
    const float* bo   = (const float*)d_in[29];
    float* out = (float*)d_out;

    float* ws = (float*)d_ws;
    float* dinv  = ws + o_dinv;
    unsigned short* g312b = (unsigned short*)(ws + o_g312);   // 1024 x 320 bf16
    unsigned short* g1024b = (unsigned short*)(ws + o_g1024); // 1024 x 1024 bf16
    float* xc    = ws + o_xc;     // [1024 x 384] fp32
    unsigned short* f1b = (unsigned short*)(ws + o_f1);       // 1024 x 1024 bf16
    float* f2    = ws + o_f2;
    float* b1v   = ws + o_b1v;
    float* b2v   = ws + o_b2v;
    int* csrOff  = (int*)(ws + o_iws);
    int* csrCur  = csrOff + (NN + 1);
    int* csrSrc  = csrCur + NN;
    int* blockSum = (int*)(ws + o_f1 + 600000);  // scratch, dead before f1b written
    int* scanFlag = blockSum + 63;
    float* bufA  = ws + o_bufA;
    float* bufB  = ws + o_bufB;
    float* T    = bufA;
    unsigned short* U16  = (unsigned short*)(bufA + 851968);
    unsigned short* Vt16 = (unsigned short*)(bufA + 2200000);  // 128 x 15360 bf16
    unsigned short* Wt   = (unsigned short*)(bufA + 3200000);  // transposed weights
    float* Wc2r = bufA + 4000000;
    float* Wc1r = bufA + 4200000;
    float* Btb  = bufA + 4400000;
    float* Pt1  = bufA + 6000000;  // t1 split-K partials (48*1024*128 fp32)
    // bf16 node pipeline (inside bufB)
    unsigned* aggb = (unsigned*)bufB;                          // NN*80 uints max
    unsigned short* h16 = (unsigned short*)(bufB + 5500000);   // up to NN*312

    unsigned short* W1t  = Wt + 0;
    unsigned short* W2t  = Wt + 12288;
    unsigned short* W3t  = Wt + 30720;
    unsigned short* Wg1t = Wt + 81920;
    unsigned short* Wg2t = Wt + 409600;
    unsigned short* Wf1t = Wt + 540672;
    unsigned short* Wf2t = Wt + 933888;

    // ---- memsets (no deps) ----
    hipMemsetAsync(Vt16, 0, (size_t)128 * 15360 * 2, stream);
    hipMemsetAsync(b1v, 0, 256 * sizeof(float), stream);   // b1v+b2v contiguous; atomic bias folds need zero
    hipMemsetAsync(csrCur, 0, NN * sizeof(int), stream);

    // ---- fused: edge histogram + all weight preprocessing (+ scan-flag zero) ----
    k_histprep<<<8508, 256, 0, stream>>>(ei + NE, csrCur, scanFlag,
                                         W1, W2, W3, Wg1, Wg2, Wf1, Wf2, Wt,
                                         Wc2, Wc1, Wc2r, Wc1r,
                                         Wxt1, Btb, bc1, bxt1, b1v,
                                         bc2, Wxt2, bxt2, b2v, emb, T);

    // ---- single-launch scan (dinv + csrOff + csrCur) ----
    k_scan_all<<<40, 1024, 0, stream>>>(csrCur, csrOff, csrCur, dinv, blockSum, scanFlag);

    // ---- fused: CSR fill + both batched GEMMs + bias C-inits ----
    k_fbi<<<2768, 256, 0, stream>>>(ei, csrCur, csrSrc, Wc2r, T, Wc1r, Btb, U16, Vt16,
                                    xc, f2, bg2, b1v, bf2);

    // ---- agg_x standalone (full occupancy) ----
    k_agg_x<<<NN, 64, 0, stream>>>(x, dinv, csrOff, csrSrc, aggb);

    // ---- fused: t1 GEMM (768 blocks, first) + GCN layer-1 GEMM (1280 blocks) ----
    k_t1_l1<<<2048, 256, 0, stream>>>(t1, Vt16, Pt1, (const unsigned short*)aggb, W1t, b1, h16);

    // ---- GCN pipeline ----
    k_agg16<<<NN, 64, 0, stream>>>((unsigned*)h16, dinv, csrOff, csrSrc, aggb, 48);
    gemm_bt<true, true, false, true><<<dim3(3, 640, 1), 256, 0, stream>>>(
        aggb, W2t, b2, h16, 156, 160, 96, 96, 96, 96, 160, 96);
    // fused: u_gather (first 1024 blocks) + agg16 F2=80
    k_agg16_ug<<<NB + NN, 128, 0, stream>>>((unsigned*)h16, dinv, csrOff, csrSrc, aggb,
                                            t2, U16, b2v, xc);
    gemm_bt<true, true, false, true><<<dim3(5, 640, 1), 256, 0, stream>>>(
        aggb, W3t, b3, h16, 312, 312, 160, 160, 160, 160, 312, 160);
    // fused: red_t1 (first 1024 blocks) + segmax
    k_segmax_red<<<2 * NB, 320, 0, stream>>>(h16, g312b, Pt1, xc);
    gemm_bt<true, true, false, true><<<dim3(16, 16, 1), 256, 0, stream>>>(
        g312b, Wg1t, bg1, g1024b, 1024, 1024, 320, 320, 320, 320, 1024, 320);

    // xc[:,0:128] = g1024 @ Wg2 + bg2   (split-K atomic)
    gemm_bt<true, false, true, false><<<dim3(2, 16, 8), 256, 0, stream>>>(
        g1024b, Wg2t, nullptr, xc + 0, 128, 128, 1024, 1024, 1024, 1024, 384, 128);

    // ---- head ----
    gemm_bt<false, true, false, true><<<dim3(16, 16, 1), 256, 0, stream>>>(
        xc, Wf1t, bf1, f1b, 1024, 1024, 384, 384, 384, 384, 1024, 384);
    gemm_bt<true, false, true, false><<<dim3(8, 16, 4), 256, 0, stream>>>(
        f1b, Wf2t, nullptr, f2, 512, 512, 1024, 1024, 1024, 1024, 512, 256);
    k_final<<<NB, 64, 0, stream>>>(f2, Wo, bo, out);
}